// Round 5
// baseline (830.904 us; speedup 1.0000x reference)
//
#include <hip/hip_runtime.h>
#include <hip/hip_bf16.h>

#define N_GENES 2000
#define SA 72
#define SH 136

typedef __attribute__((ext_vector_type(8))) short frag8;
typedef __attribute__((ext_vector_type(4))) float facc4;

static __device__ __forceinline__ unsigned short f2bf(float f) {
    unsigned int u = __float_as_uint(f);
    unsigned int r = (u + 0x7FFFu + ((u >> 16) & 1u)) >> 16;
    return (unsigned short)r;
}
static __device__ __forceinline__ ushort2 pk2(float a, float b) {
    __hip_bfloat162 r = __float22bfloat162_rn(float2{a, b});
    return *(ushort2*)&r;
}

// ---- weight transposes + deg/counter zeroing ----
__global__ void prep(const float* __restrict__ ip_w,
                     const float* __restrict__ ws_f, const float* __restrict__ wd_f,
                     const float* __restrict__ ws_p, const float* __restrict__ wd_p,
                     unsigned short* __restrict__ Bt1,
                     unsigned short* __restrict__ Bf, unsigned short* __restrict__ Bp,
                     int* __restrict__ deg, unsigned int* __restrict__ counter, int n2) {
    int idx = blockIdx.x * blockDim.x + threadIdx.x;
    if (idx < n2) deg[idx] = 0;
    if (idx == 0) counter[0] = 0u;
    if (idx < 128 * 2048) {
        int nrow = idx >> 11, k = idx & 2047;
        unsigned short v = 0;
        if (k < N_GENES) v = f2bf(ip_w[(size_t)k * 128 + nrow]);
        Bt1[idx] = v;
    } else {
        int q = idx - 128 * 2048;
        if (q >= 2 * 256 * 128) return;
        int g = q >> 15;
        int r = (q >> 7) & 255;
        int k = q & 127;
        const float* w = (g == 0) ? (r < 128 ? ws_f : wd_f) : (r < 128 ? ws_p : wd_p);
        (g == 0 ? Bf : Bp)[(r << 7) | k] = f2bf(w[k * 128 + (r & 127)]);
    }
}

// ---- mega dispatch: blocks [0,gemmBlocks) run the fused GEMM;
//      blocks [gemmBlocks,..) run the degree histogram (hidden under the GEMM). ----
__global__ __launch_bounds__(256) void gemm_deg(const float* __restrict__ A,
                                                const unsigned short* __restrict__ Bt,
                                                const float* __restrict__ bias,
                                                const unsigned short* __restrict__ Bf,
                                                const unsigned short* __restrict__ Bp,
                                                unsigned short* __restrict__ Cf,
                                                unsigned short* __restrict__ Cp,
                                                int M, int K, int gemmBlocks,
                                                const int* __restrict__ dst_f, int Ef,
                                                const int* __restrict__ dst_p, int Ep,
                                                int* __restrict__ deg, int N) {
    if (blockIdx.x >= gemmBlocks) {
        int e = (blockIdx.x - gemmBlocks) * 256 + threadIdx.x;
        if (e < Ef) atomicAdd(&deg[dst_f[e]], 1);
        else if (e < Ef + Ep) atomicAdd(&deg[N + dst_p[e - Ef]], 1);
        return;
    }
    const int Kpad = 2048;
    __shared__ __align__(16) unsigned short lA[64 * SA];
    __shared__ __align__(16) unsigned short lH[64 * SH];
    int t = threadIdx.x, lane = t & 63, wv = t >> 6;
    int lr = lane & 15, lq = lane >> 4;
    facc4 acc[4][2];
#pragma unroll
    for (int i = 0; i < 4; i++)
#pragma unroll
        for (int j = 0; j < 2; j++) acc[i][j] = (facc4){0.f, 0.f, 0.f, 0.f};
    int row_base = blockIdx.x * 64;

    int ar_r[4], ar_c[4];
    const float* ar_p[4];
#pragma unroll
    for (int j = 0; j < 4; j++) {
        int q = j * 256 + t;
        ar_r[j] = q >> 4;
        ar_c[j] = (q & 15) * 4;
        int rg = row_base + ar_r[j];
        if (rg >= M) rg = M - 1;
        ar_p[j] = A + (size_t)rg * K + ar_c[j];
    }
    const unsigned short* bp[4];
#pragma unroll
    for (int ks = 0; ks < 2; ks++)
#pragma unroll
        for (int ni = 0; ni < 2; ni++) {
            int col = wv * 32 + ni * 16 + lr;
            bp[ks * 2 + ni] = Bt + (size_t)col * Kpad + ks * 32 + lq * 8;
        }

    float4 ar[4];
    frag8 bfr[4];
#pragma unroll
    for (int j = 0; j < 4; j++) ar[j] = *(const float4*)(ar_p[j]);
#pragma unroll
    for (int f = 0; f < 4; f++) bfr[f] = *(const frag8*)(bp[f]);

    for (int k0 = 0; k0 < Kpad; k0 += 64) {
        __syncthreads();
#pragma unroll
        for (int j = 0; j < 4; j++) {
            ushort2 u01 = pk2(ar[j].x, ar[j].y);
            ushort2 u23 = pk2(ar[j].z, ar[j].w);
            ushort4 u = {u01.x, u01.y, u23.x, u23.y};
            *(ushort4*)&lA[ar_r[j] * SA + ar_c[j]] = u;
        }
        __syncthreads();
        int kn = k0 + 64;
        frag8 bfn[4];
        if (kn < Kpad) {
#pragma unroll
            for (int j = 0; j < 4; j++) {
                int kk = kn + ar_c[j];
                float4 v = {0.f, 0.f, 0.f, 0.f};
                if (kk < K) v = *(const float4*)(ar_p[j] + kn);
                ar[j] = v;
            }
#pragma unroll
            for (int f = 0; f < 4; f++) bfn[f] = *(const frag8*)(bp[f] + kn);
        }
#pragma unroll
        for (int ks = 0; ks < 2; ks++) {
            frag8 af[4];
#pragma unroll
            for (int mi = 0; mi < 4; mi++)
                af[mi] = *(const frag8*)&lA[(mi * 16 + lr) * SA + ks * 32 + lq * 8];
#pragma unroll
            for (int mi = 0; mi < 4; mi++)
#pragma unroll
                for (int ni = 0; ni < 2; ni++)
                    acc[mi][ni] = __builtin_amdgcn_mfma_f32_16x16x32_bf16(af[mi], bfr[ks * 2 + ni], acc[mi][ni], 0, 0, 0);
        }
        if (kn < Kpad) {
#pragma unroll
            for (int f = 0; f < 4; f++) bfr[f] = bfn[f];
        }
    }
    __syncthreads();
#pragma unroll
    for (int mi = 0; mi < 4; mi++) {
#pragma unroll
        for (int r = 0; r < 4; r++) {
            int row = mi * 16 + lq * 4 + r;
#pragma unroll
            for (int ni = 0; ni < 2; ni++) {
                int col = wv * 32 + ni * 16 + lr;
                lH[row * SH + col] = f2bf(acc[mi][ni][r] + bias[col]);
            }
        }
    }
    __syncthreads();
#pragma unroll 1
    for (int g = 0; g < 2; g++) {
        const unsigned short* B2 = g ? Bp : Bf;
        unsigned short* Cb = g ? Cp : Cf;
        facc4 a2[4][4];
#pragma unroll
        for (int i = 0; i < 4; i++)
#pragma unroll
            for (int j = 0; j < 4; j++) a2[i][j] = (facc4){0.f, 0.f, 0.f, 0.f};
#pragma unroll
        for (int ks = 0; ks < 4; ks++) {
            frag8 af[4], bf[4];
#pragma unroll
            for (int mi = 0; mi < 4; mi++)
                af[mi] = *(const frag8*)&lH[(mi * 16 + lr) * SH + ks * 32 + lq * 8];
#pragma unroll
            for (int ni = 0; ni < 4; ni++)
                bf[ni] = *(const frag8*)(B2 + ((wv * 64 + ni * 16 + lr) << 7) + ks * 32 + lq * 8);
#pragma unroll
            for (int mi = 0; mi < 4; mi++)
#pragma unroll
                for (int ni = 0; ni < 4; ni++)
                    a2[mi][ni] = __builtin_amdgcn_mfma_f32_16x16x32_bf16(af[mi], bf[ni], a2[mi][ni], 0, 0, 0);
        }
#pragma unroll
        for (int mi = 0; mi < 4; mi++) {
#pragma unroll
            for (int r = 0; r < 4; r++) {
                int row = row_base + mi * 16 + lq * 4 + r;
                if (row < M) {
#pragma unroll
                    for (int ni = 0; ni < 4; ni++) {
                        int col = wv * 64 + ni * 16 + lr;
                        Cb[(size_t)row * 256 + col] = f2bf(a2[mi][ni][r]);
                    }
                }
            }
        }
    }
}

// ---- unordered segment assignment: offs[i]=cur[i]=atomic base (wave-aggregated).
//      Replaces the 3-dispatch exclusive scan; segments need not be node-ordered. ----
__global__ __launch_bounds__(256) void seg_assign(const int* __restrict__ deg,
                                                  int* __restrict__ offs,
                                                  int* __restrict__ cur,
                                                  unsigned int* __restrict__ counter, int n2) {
    int i = blockIdx.x * 256 + threadIdx.x;
    int lane = threadIdx.x & 63;
    int c = (i < n2) ? deg[i] : 0;
    int incl = c;
#pragma unroll
    for (int o = 1; o < 64; o <<= 1) {
        int y = __shfl_up(incl, o);
        if (lane >= o) incl += y;
    }
    int wtot = __shfl(incl, 63);
    int base = 0;
    if (lane == 63) base = (int)atomicAdd(counter, (unsigned int)wtot);
    base = __shfl(base, 63);
    int start = base + incl - c;
    if (i < n2) { offs[i] = start; cur[i] = start; }
}

// ---- fill CSR-ordered (src, weight) int2 pairs via per-node cursor ----
__global__ void fill2(const int* __restrict__ src_f, const int* __restrict__ dst_f,
                      const float* __restrict__ ew_f, int Ef,
                      const int* __restrict__ src_p, const int* __restrict__ dst_p,
                      const float* __restrict__ ew_p, int Ep,
                      int* __restrict__ cur, int2* __restrict__ srcw, int N) {
    int e = blockIdx.x * blockDim.x + threadIdx.x;
    if (e >= Ef + Ep) return;
    int g = (e >= Ef);
    int ee = g ? e - Ef : e;
    int d = g ? dst_p[ee] : dst_f[ee];
    int node = g ? N + d : d;
    int p = atomicAdd(&cur[node], 1);
    int s = g ? src_p[ee] : src_f[ee];
    float w = g ? ew_p[ee] : ew_f[ee];
    srcw[p] = make_int2(s, __float_as_int(w));
}

// ---- per-node GAT aggregation for one graph (2 dims/lane, 6/4 pipeline) ----
static __device__ __forceinline__ float2 gat_node(const unsigned short* __restrict__ hshd,
                                                  const float* __restrict__ wedge,
                                                  const float* __restrict__ attn,
                                                  const float* __restrict__ bias,
                                                  const int2* __restrict__ srcw,
                                                  int s, int cnt, int onode, int d2) {
    const float LOG2E = 1.4426950408889634f;
    const float2 wv = *(const float2*)&wedge[d2];
    float2 av = *(const float2*)&attn[d2];
    av.x *= LOG2E; av.y *= LOG2E;
    unsigned int hdraw = *(const unsigned int*)&hshd[(size_t)onode * 256 + 128 + d2];
    const float hd0 = __uint_as_float(hdraw << 16);
    const float hd1 = __uint_as_float(hdraw & 0xffff0000u);
    float m = -INFINITY, l = 0.f, acc0 = 0.f, acc1 = 0.f;
    if (cnt > 0) {
        int last = s + cnt - 1;
        auto CL = [last](int j) { return j > last ? last : j; };
        int2 e0 = srcw[s], e1 = srcw[CL(s + 1)], e2 = srcw[CL(s + 2)], e3 = srcw[CL(s + 3)];
        int2 e4 = srcw[CL(s + 4)], e5 = srcw[CL(s + 5)];
        unsigned int hr0 = *(const unsigned int*)&hshd[(size_t)e0.x * 256 + d2];
        unsigned int hr1 = *(const unsigned int*)&hshd[(size_t)e1.x * 256 + d2];
        unsigned int hr2 = *(const unsigned int*)&hshd[(size_t)e2.x * 256 + d2];
        unsigned int hr3 = *(const unsigned int*)&hshd[(size_t)e3.x * 256 + d2];
        for (int i = 0; i < cnt; i += 2) {
            int2 ea = srcw[CL(s + i + 6)], eb = srcw[CL(s + i + 7)];
            unsigned int hr4 = *(const unsigned int*)&hshd[(size_t)e4.x * 256 + d2];
            unsigned int hr5 = *(const unsigned int*)&hshd[(size_t)e5.x * 256 + d2];
            {
                float h0 = __uint_as_float(hr0 << 16);
                float h1 = __uint_as_float(hr0 & 0xffff0000u);
                float w = __int_as_float(e0.y);
                float z0 = fmaf(w, wv.x, h0 + hd0); z0 = (z0 > 0.f) ? z0 : 0.2f * z0;
                float z1 = fmaf(w, wv.y, h1 + hd1); z1 = (z1 > 0.f) ? z1 : 0.2f * z1;
                float t = z0 * av.x + z1 * av.y;
                t += __shfl_xor(t, 1);
                t += __shfl_xor(t, 2);
                t += __shfl_xor(t, 4);
                t += __shfl_xor(t, 8);
                float mn = fmaxf(m, t);
                float sc = __builtin_amdgcn_exp2f(m - mn);
                float p = __builtin_amdgcn_exp2f(t - mn);
                l = l * sc + p;
                acc0 = acc0 * sc + p * h0;
                acc1 = acc1 * sc + p * h1;
                m = mn;
            }
            if (i + 1 < cnt) {
                float h0 = __uint_as_float(hr1 << 16);
                float h1 = __uint_as_float(hr1 & 0xffff0000u);
                float w = __int_as_float(e1.y);
                float z0 = fmaf(w, wv.x, h0 + hd0); z0 = (z0 > 0.f) ? z0 : 0.2f * z0;
                float z1 = fmaf(w, wv.y, h1 + hd1); z1 = (z1 > 0.f) ? z1 : 0.2f * z1;
                float t = z0 * av.x + z1 * av.y;
                t += __shfl_xor(t, 1);
                t += __shfl_xor(t, 2);
                t += __shfl_xor(t, 4);
                t += __shfl_xor(t, 8);
                float mn = fmaxf(m, t);
                float sc = __builtin_amdgcn_exp2f(m - mn);
                float p = __builtin_amdgcn_exp2f(t - mn);
                l = l * sc + p;
                acc0 = acc0 * sc + p * h0;
                acc1 = acc1 * sc + p * h1;
                m = mn;
            }
            e0 = e2; e1 = e3; e2 = e4; e3 = e5; e4 = ea; e5 = eb;
            hr0 = hr2; hr1 = hr3; hr2 = hr4; hr3 = hr5;
        }
    }
    float inv = 1.f / (l + 1e-16f);
    const float2 bv = *(const float2*)&bias[d2];
    return float2{acc0 * inv + bv.x, acc1 * inv + bv.y};
}

// ---- fused GAT(both graphs) + combine + ELU + LayerNorm: one wave per node ----
__global__ __launch_bounds__(256) void gat_final(const int* __restrict__ offs,
                                                 const int* __restrict__ deg,
                                                 const int2* __restrict__ srcw,
                                                 const unsigned short* __restrict__ hshd_f,
                                                 const unsigned short* __restrict__ hshd_p,
                                                 const float* __restrict__ wedge_f,
                                                 const float* __restrict__ attn_f,
                                                 const float* __restrict__ bias_f,
                                                 const float* __restrict__ wedge_p,
                                                 const float* __restrict__ attn_p,
                                                 const float* __restrict__ bias_p,
                                                 const float* __restrict__ alpha_p,
                                                 const float* __restrict__ scale,
                                                 const float* __restrict__ beta,
                                                 float* __restrict__ out, int N) {
    int node = blockIdx.x * 4 + (threadIdx.x >> 6);
    if (node >= N) return;
    int lane = threadIdx.x & 63;
    int d2 = lane * 2;
    float2 f = gat_node(hshd_f, wedge_f, attn_f, bias_f, srcw,
                        offs[node], deg[node], node, d2);
    float2 p = gat_node(hshd_p, wedge_p, attn_p, bias_p, srcw,
                        offs[N + node], deg[N + node], node, d2);
    float a = *alpha_p;
    float x0 = (1.f - a) * f.x + a * p.x;
    float x1 = (1.f - a) * f.y + a * p.y;
    x0 = (x0 > 0.f) ? x0 : expm1f(x0);
    x1 = (x1 > 0.f) ? x1 : expm1f(x1);
    float sm = x0 + x1;
#pragma unroll
    for (int o = 32; o >= 1; o >>= 1) sm += __shfl_xor(sm, o);
    float mu = sm * (1.f / 128.f);
    float d0 = x0 - mu, d1 = x1 - mu;
    float v = d0 * d0 + d1 * d1;
#pragma unroll
    for (int o = 32; o >= 1; o >>= 1) v += __shfl_xor(v, o);
    float rstd = rsqrtf(v * (1.f / 128.f) + 1e-6f);
    const float2 sv = *(const float2*)&scale[d2];
    const float2 bv = *(const float2*)&beta[d2];
    float2 o2;
    o2.x = d0 * rstd * sv.x + bv.x;
    o2.y = d1 * rstd * sv.y + bv.y;
    *(float2*)&out[(size_t)node * 128 + d2] = o2;
}

extern "C" void kernel_launch(void* const* d_in, const int* in_sizes, int n_in,
                              void* d_out, int out_size, void* d_ws, size_t ws_size,
                              hipStream_t stream) {
    const float* nf = (const float*)d_in[0];
    const int* fei = (const int*)d_in[1];
    const float* few = (const float*)d_in[2];
    const int* pei = (const int*)d_in[3];
    const float* pew = (const float*)d_in[4];
    const float* alpha = (const float*)d_in[5];
    const float* ip_w = (const float*)d_in[6];
    const float* ip_b = (const float*)d_in[7];
    const float* gf_wsrc = (const float*)d_in[8];
    const float* gf_wdst = (const float*)d_in[9];
    const float* gf_wedge = (const float*)d_in[10];
    const float* gf_attn = (const float*)d_in[11];
    const float* gf_bias = (const float*)d_in[12];
    const float* gp_wsrc = (const float*)d_in[13];
    const float* gp_wdst = (const float*)d_in[14];
    const float* gp_wedge = (const float*)d_in[15];
    const float* gp_attn = (const float*)d_in[16];
    const float* gp_bias = (const float*)d_in[17];
    const float* ln_scale = (const float*)d_in[18];
    const float* ln_bias = (const float*)d_in[19];

    const int N = in_sizes[0] / N_GENES;
    const int Ef = in_sizes[1] / 2;
    const int Ep = in_sizes[3] / 2;
    const int Etot = Ef + Ep;
    const int n2 = 2 * N;

    char* base = (char*)d_ws;
    size_t off = 0;
    auto carve = [&](size_t bytes) -> char* {
        char* p = base + off;
        off = (off + bytes + 255) & ~(size_t)255;
        return p;
    };
    unsigned short* Bt1 = (unsigned short*)carve((size_t)128 * 2048 * 2);
    unsigned short* Bf = (unsigned short*)carve(256 * 128 * 2);
    unsigned short* Bp = (unsigned short*)carve(256 * 128 * 2);
    unsigned short* hshd_f = (unsigned short*)carve((size_t)N * 256 * 2);
    unsigned short* hshd_p = (unsigned short*)carve((size_t)N * 256 * 2);
    int* deg = (int*)carve((size_t)n2 * 4);
    int* offs = (int*)carve((size_t)n2 * 4);
    int* cur = (int*)carve((size_t)n2 * 4);
    unsigned int* counter = (unsigned int*)carve(4);
    int2* srcw = (int2*)carve((size_t)Etot * 8);
    float* out_f = (float*)d_out;

    const int* src_f = fei;
    const int* dst_f = fei + Ef;
    const int* src_p = pei;
    const int* dst_p = pei + Ep;

    prep<<<(128 * 2048 + 2 * 256 * 128 + 255) / 256, 256, 0, stream>>>(
        ip_w, gf_wsrc, gf_wdst, gp_wsrc, gp_wdst, Bt1, Bf, Bp, deg, counter, n2);

    int gb1 = (N + 63) / 64;
    int degb = (Etot + 255) / 256;
    gemm_deg<<<gb1 + degb, 256, 0, stream>>>(nf, Bt1, ip_b, Bf, Bp, hshd_f, hshd_p,
                                             N, N_GENES, gb1,
                                             dst_f, Ef, dst_p, Ep, deg, N);

    seg_assign<<<(n2 + 255) / 256, 256, 0, stream>>>(deg, offs, cur, counter, n2);

    fill2<<<(Etot + 255) / 256, 256, 0, stream>>>(src_f, dst_f, few, Ef, src_p, dst_p, pew, Ep,
                                                  cur, srcw, N);

    gat_final<<<(N + 3) / 4, 256, 0, stream>>>(offs, deg, srcw, hshd_f, hshd_p,
                                               gf_wedge, gf_attn, gf_bias,
                                               gp_wedge, gp_attn, gp_bias,
                                               alpha, ln_scale, ln_bias, out_f, N);
    (void)ws_size; (void)n_in; (void)out_size;
}

// Round 6
// 823.737 us; speedup vs baseline: 1.0087x; 1.0087x over previous
//
#include <hip/hip_runtime.h>
#include <hip/hip_bf16.h>

#define N_GENES 2000
#define SA 72
#define SH 136

typedef __attribute__((ext_vector_type(8))) short frag8;
typedef __attribute__((ext_vector_type(4))) float facc4;

static __device__ __forceinline__ unsigned short f2bf(float f) {
    unsigned int u = __float_as_uint(f);
    unsigned int r = (u + 0x7FFFu + ((u >> 16) & 1u)) >> 16;
    return (unsigned short)r;
}
static __device__ __forceinline__ ushort2 pk2(float a, float b) {
    __hip_bfloat162 r = __float22bfloat162_rn(float2{a, b});
    return *(ushort2*)&r;
}

// ---- weight transposes + deg/counter zeroing ----
__global__ void prep(const float* __restrict__ ip_w,
                     const float* __restrict__ ws_f, const float* __restrict__ wd_f,
                     const float* __restrict__ ws_p, const float* __restrict__ wd_p,
                     unsigned short* __restrict__ Bt1,
                     unsigned short* __restrict__ Bf, unsigned short* __restrict__ Bp,
                     int* __restrict__ deg, unsigned int* __restrict__ counter, int n2) {
    int idx = blockIdx.x * blockDim.x + threadIdx.x;
    if (idx < n2) deg[idx] = 0;
    if (idx == 0) counter[0] = 0u;
    if (idx < 128 * 2048) {
        int nrow = idx >> 11, k = idx & 2047;
        unsigned short v = 0;
        if (k < N_GENES) v = f2bf(ip_w[(size_t)k * 128 + nrow]);
        Bt1[idx] = v;
    } else {
        int q = idx - 128 * 2048;
        if (q >= 2 * 256 * 128) return;
        int g = q >> 15;
        int r = (q >> 7) & 255;
        int k = q & 127;
        const float* w = (g == 0) ? (r < 128 ? ws_f : wd_f) : (r < 128 ? ws_p : wd_p);
        (g == 0 ? Bf : Bp)[(r << 7) | k] = f2bf(w[k * 128 + (r & 127)]);
    }
}

// ---- mega dispatch: blocks [0,gemmBlocks) run the fused GEMM;
//      blocks [gemmBlocks,..) run the degree histogram (hidden under the GEMM). ----
__global__ __launch_bounds__(256) void gemm_deg(const float* __restrict__ A,
                                                const unsigned short* __restrict__ Bt,
                                                const float* __restrict__ bias,
                                                const unsigned short* __restrict__ Bf,
                                                const unsigned short* __restrict__ Bp,
                                                unsigned short* __restrict__ Cf,
                                                unsigned short* __restrict__ Cp,
                                                int M, int K, int gemmBlocks,
                                                const int* __restrict__ dst_f, int Ef,
                                                const int* __restrict__ dst_p, int Ep,
                                                int* __restrict__ deg, int N) {
    if (blockIdx.x >= gemmBlocks) {
        int e = (blockIdx.x - gemmBlocks) * 256 + threadIdx.x;
        if (e < Ef) atomicAdd(&deg[dst_f[e]], 1);
        else if (e < Ef + Ep) atomicAdd(&deg[N + dst_p[e - Ef]], 1);
        return;
    }
    const int Kpad = 2048;
    __shared__ __align__(16) unsigned short lA[64 * SA];
    __shared__ __align__(16) unsigned short lH[64 * SH];
    int t = threadIdx.x, lane = t & 63, wv = t >> 6;
    int lr = lane & 15, lq = lane >> 4;
    facc4 acc[4][2];
#pragma unroll
    for (int i = 0; i < 4; i++)
#pragma unroll
        for (int j = 0; j < 2; j++) acc[i][j] = (facc4){0.f, 0.f, 0.f, 0.f};
    int row_base = blockIdx.x * 64;

    int ar_r[4], ar_c[4];
    const float* ar_p[4];
#pragma unroll
    for (int j = 0; j < 4; j++) {
        int q = j * 256 + t;
        ar_r[j] = q >> 4;
        ar_c[j] = (q & 15) * 4;
        int rg = row_base + ar_r[j];
        if (rg >= M) rg = M - 1;
        ar_p[j] = A + (size_t)rg * K + ar_c[j];
    }
    const unsigned short* bp[4];
#pragma unroll
    for (int ks = 0; ks < 2; ks++)
#pragma unroll
        for (int ni = 0; ni < 2; ni++) {
            int col = wv * 32 + ni * 16 + lr;
            bp[ks * 2 + ni] = Bt + (size_t)col * Kpad + ks * 32 + lq * 8;
        }

    float4 ar[4];
    frag8 bfr[4];
#pragma unroll
    for (int j = 0; j < 4; j++) ar[j] = *(const float4*)(ar_p[j]);
#pragma unroll
    for (int f = 0; f < 4; f++) bfr[f] = *(const frag8*)(bp[f]);

    for (int k0 = 0; k0 < Kpad; k0 += 64) {
        __syncthreads();
#pragma unroll
        for (int j = 0; j < 4; j++) {
            ushort2 u01 = pk2(ar[j].x, ar[j].y);
            ushort2 u23 = pk2(ar[j].z, ar[j].w);
            ushort4 u = {u01.x, u01.y, u23.x, u23.y};
            *(ushort4*)&lA[ar_r[j] * SA + ar_c[j]] = u;
        }
        __syncthreads();
        int kn = k0 + 64;
        frag8 bfn[4];
        if (kn < Kpad) {
#pragma unroll
            for (int j = 0; j < 4; j++) {
                int kk = kn + ar_c[j];
                float4 v = {0.f, 0.f, 0.f, 0.f};
                if (kk < K) v = *(const float4*)(ar_p[j] + kn);
                ar[j] = v;
            }
#pragma unroll
            for (int f = 0; f < 4; f++) bfn[f] = *(const frag8*)(bp[f] + kn);
        }
#pragma unroll
        for (int ks = 0; ks < 2; ks++) {
            frag8 af[4];
#pragma unroll
            for (int mi = 0; mi < 4; mi++)
                af[mi] = *(const frag8*)&lA[(mi * 16 + lr) * SA + ks * 32 + lq * 8];
#pragma unroll
            for (int mi = 0; mi < 4; mi++)
#pragma unroll
                for (int ni = 0; ni < 2; ni++)
                    acc[mi][ni] = __builtin_amdgcn_mfma_f32_16x16x32_bf16(af[mi], bfr[ks * 2 + ni], acc[mi][ni], 0, 0, 0);
        }
        if (kn < Kpad) {
#pragma unroll
            for (int f = 0; f < 4; f++) bfr[f] = bfn[f];
        }
    }
    __syncthreads();
#pragma unroll
    for (int mi = 0; mi < 4; mi++) {
#pragma unroll
        for (int r = 0; r < 4; r++) {
            int row = mi * 16 + lq * 4 + r;
#pragma unroll
            for (int ni = 0; ni < 2; ni++) {
                int col = wv * 32 + ni * 16 + lr;
                lH[row * SH + col] = f2bf(acc[mi][ni][r] + bias[col]);
            }
        }
    }
    __syncthreads();
#pragma unroll 1
    for (int g = 0; g < 2; g++) {
        const unsigned short* B2 = g ? Bp : Bf;
        unsigned short* Cb = g ? Cp : Cf;
        facc4 a2[4][4];
#pragma unroll
        for (int i = 0; i < 4; i++)
#pragma unroll
            for (int j = 0; j < 4; j++) a2[i][j] = (facc4){0.f, 0.f, 0.f, 0.f};
#pragma unroll
        for (int ks = 0; ks < 4; ks++) {
            frag8 af[4], bf[4];
#pragma unroll
            for (int mi = 0; mi < 4; mi++)
                af[mi] = *(const frag8*)&lH[(mi * 16 + lr) * SH + ks * 32 + lq * 8];
#pragma unroll
            for (int ni = 0; ni < 4; ni++)
                bf[ni] = *(const frag8*)(B2 + ((wv * 64 + ni * 16 + lr) << 7) + ks * 32 + lq * 8);
#pragma unroll
            for (int mi = 0; mi < 4; mi++)
#pragma unroll
                for (int ni = 0; ni < 4; ni++)
                    a2[mi][ni] = __builtin_amdgcn_mfma_f32_16x16x32_bf16(af[mi], bf[ni], a2[mi][ni], 0, 0, 0);
        }
#pragma unroll
        for (int mi = 0; mi < 4; mi++) {
#pragma unroll
            for (int r = 0; r < 4; r++) {
                int row = row_base + mi * 16 + lq * 4 + r;
                if (row < M) {
#pragma unroll
                    for (int ni = 0; ni < 4; ni++) {
                        int col = wv * 64 + ni * 16 + lr;
                        Cb[(size_t)row * 256 + col] = f2bf(a2[mi][ni][r]);
                    }
                }
            }
        }
    }
}

// ---- unordered segment assignment: offs[i]=cur[i]=atomic base (wave-aggregated).
//      Replaces the 3-dispatch exclusive scan; segments need not be node-ordered. ----
__global__ __launch_bounds__(256) void seg_assign(const int* __restrict__ deg,
                                                  int* __restrict__ offs,
                                                  int* __restrict__ cur,
                                                  unsigned int* __restrict__ counter, int n2) {
    int i = blockIdx.x * 256 + threadIdx.x;
    int lane = threadIdx.x & 63;
    int c = (i < n2) ? deg[i] : 0;
    int incl = c;
#pragma unroll
    for (int o = 1; o < 64; o <<= 1) {
        int y = __shfl_up(incl, o);
        if (lane >= o) incl += y;
    }
    int wtot = __shfl(incl, 63);
    int base = 0;
    if (lane == 63) base = (int)atomicAdd(counter, (unsigned int)wtot);
    base = __shfl(base, 63);
    int start = base + incl - c;
    if (i < n2) { offs[i] = start; cur[i] = start; }
}

// ---- fill CSR-ordered (src, weight) int2 pairs via per-node cursor ----
__global__ void fill2(const int* __restrict__ src_f, const int* __restrict__ dst_f,
                      const float* __restrict__ ew_f, int Ef,
                      const int* __restrict__ src_p, const int* __restrict__ dst_p,
                      const float* __restrict__ ew_p, int Ep,
                      int* __restrict__ cur, int2* __restrict__ srcw, int N) {
    int e = blockIdx.x * blockDim.x + threadIdx.x;
    if (e >= Ef + Ep) return;
    int g = (e >= Ef);
    int ee = g ? e - Ef : e;
    int d = g ? dst_p[ee] : dst_f[ee];
    int node = g ? N + d : d;
    int p = atomicAdd(&cur[node], 1);
    int s = g ? src_p[ee] : src_f[ee];
    float w = g ? ew_p[ee] : ew_f[ee];
    srcw[p] = make_int2(s, __float_as_int(w));
}

// ---- GAT: one wave per dst node, 2 dims/lane (head = 16-lane group), 6/4 pipeline ----
__global__ __launch_bounds__(256) void gat2(const int* __restrict__ offs,
                                            const int* __restrict__ deg,
                                            const int2* __restrict__ srcw,
                                            const unsigned short* __restrict__ hshd_f,
                                            const unsigned short* __restrict__ hshd_p,
                                            const float* __restrict__ wedge_f,
                                            const float* __restrict__ attn_f,
                                            const float* __restrict__ bias_f,
                                            const float* __restrict__ wedge_p,
                                            const float* __restrict__ attn_p,
                                            const float* __restrict__ bias_p,
                                            float* __restrict__ out_full,
                                            float* __restrict__ out_pruned, int N) {
    int node = blockIdx.x * 4 + (threadIdx.x >> 6);
    if (node >= 2 * N) return;
    int g = node >= N;
    int onode = g ? node - N : node;
    const unsigned short* hshd = g ? hshd_p : hshd_f;
    const float* wedge = g ? wedge_p : wedge_f;
    const float* attn = g ? attn_p : attn_f;
    const float* bias = g ? bias_p : bias_f;
    float* out = g ? out_pruned : out_full;
    int lane = threadIdx.x & 63;
    int d2 = lane * 2;
    const float LOG2E = 1.4426950408889634f;
    const float2 wv = *(const float2*)&wedge[d2];
    float2 av = *(const float2*)&attn[d2];
    av.x *= LOG2E; av.y *= LOG2E;
    unsigned int hdraw = *(const unsigned int*)&hshd[(size_t)onode * 256 + 128 + d2];
    const float hd0 = __uint_as_float(hdraw << 16);
    const float hd1 = __uint_as_float(hdraw & 0xffff0000u);
    int s = offs[node], cnt = deg[node];
    float m = -INFINITY, l = 0.f, acc0 = 0.f, acc1 = 0.f;
    if (cnt > 0) {
        int last = s + cnt - 1;
        auto CL = [last](int j) { return j > last ? last : j; };
        int2 e0 = srcw[s], e1 = srcw[CL(s + 1)], e2 = srcw[CL(s + 2)], e3 = srcw[CL(s + 3)];
        int2 e4 = srcw[CL(s + 4)], e5 = srcw[CL(s + 5)];
        unsigned int hr0 = *(const unsigned int*)&hshd[(size_t)e0.x * 256 + d2];
        unsigned int hr1 = *(const unsigned int*)&hshd[(size_t)e1.x * 256 + d2];
        unsigned int hr2 = *(const unsigned int*)&hshd[(size_t)e2.x * 256 + d2];
        unsigned int hr3 = *(const unsigned int*)&hshd[(size_t)e3.x * 256 + d2];
        for (int i = 0; i < cnt; i += 2) {
            int2 ea = srcw[CL(s + i + 6)], eb = srcw[CL(s + i + 7)];
            unsigned int hr4 = *(const unsigned int*)&hshd[(size_t)e4.x * 256 + d2];
            unsigned int hr5 = *(const unsigned int*)&hshd[(size_t)e5.x * 256 + d2];
            {
                float h0 = __uint_as_float(hr0 << 16);
                float h1 = __uint_as_float(hr0 & 0xffff0000u);
                float w = __int_as_float(e0.y);
                float z0 = fmaf(w, wv.x, h0 + hd0); z0 = (z0 > 0.f) ? z0 : 0.2f * z0;
                float z1 = fmaf(w, wv.y, h1 + hd1); z1 = (z1 > 0.f) ? z1 : 0.2f * z1;
                float t = z0 * av.x + z1 * av.y;
                t += __shfl_xor(t, 1);
                t += __shfl_xor(t, 2);
                t += __shfl_xor(t, 4);
                t += __shfl_xor(t, 8);
                float mn = fmaxf(m, t);
                float sc = __builtin_amdgcn_exp2f(m - mn);
                float p = __builtin_amdgcn_exp2f(t - mn);
                l = l * sc + p;
                acc0 = acc0 * sc + p * h0;
                acc1 = acc1 * sc + p * h1;
                m = mn;
            }
            if (i + 1 < cnt) {
                float h0 = __uint_as_float(hr1 << 16);
                float h1 = __uint_as_float(hr1 & 0xffff0000u);
                float w = __int_as_float(e1.y);
                float z0 = fmaf(w, wv.x, h0 + hd0); z0 = (z0 > 0.f) ? z0 : 0.2f * z0;
                float z1 = fmaf(w, wv.y, h1 + hd1); z1 = (z1 > 0.f) ? z1 : 0.2f * z1;
                float t = z0 * av.x + z1 * av.y;
                t += __shfl_xor(t, 1);
                t += __shfl_xor(t, 2);
                t += __shfl_xor(t, 4);
                t += __shfl_xor(t, 8);
                float mn = fmaxf(m, t);
                float sc = __builtin_amdgcn_exp2f(m - mn);
                float p = __builtin_amdgcn_exp2f(t - mn);
                l = l * sc + p;
                acc0 = acc0 * sc + p * h0;
                acc1 = acc1 * sc + p * h1;
                m = mn;
            }
            e0 = e2; e1 = e3; e2 = e4; e3 = e5; e4 = ea; e5 = eb;
            hr0 = hr2; hr1 = hr3; hr2 = hr4; hr3 = hr5;
        }
    }
    float inv = 1.f / (l + 1e-16f);
    const float2 bv = *(const float2*)&bias[d2];
    float2 o;
    o.x = acc0 * inv + bv.x;
    o.y = acc1 * inv + bv.y;
    *(float2*)&out[(size_t)onode * 128 + d2] = o;
}

// ---- combine + ELU + LayerNorm (in-place on d_out holding h_pruned), 2 dims/lane ----
__global__ __launch_bounds__(256) void final_kernel(const float* __restrict__ hf,
                                                    float* __restrict__ out,
                                                    const float* __restrict__ alpha_p,
                                                    const float* __restrict__ scale,
                                                    const float* __restrict__ beta, int n) {
    int node = blockIdx.x * 4 + (threadIdx.x >> 6);
    if (node >= n) return;
    int lane = threadIdx.x & 63;
    int d2 = lane * 2;
    float a = *alpha_p;
    float2 f = *(const float2*)&hf[(size_t)node * 128 + d2];
    float2 p = *(const float2*)&out[(size_t)node * 128 + d2];
    float x0 = (1.f - a) * f.x + a * p.x;
    float x1 = (1.f - a) * f.y + a * p.y;
    x0 = (x0 > 0.f) ? x0 : expm1f(x0);
    x1 = (x1 > 0.f) ? x1 : expm1f(x1);
    float sm = x0 + x1;
#pragma unroll
    for (int o = 32; o >= 1; o >>= 1) sm += __shfl_xor(sm, o);
    float mu = sm * (1.f / 128.f);
    float d0 = x0 - mu, d1 = x1 - mu;
    float v = d0 * d0 + d1 * d1;
#pragma unroll
    for (int o = 32; o >= 1; o >>= 1) v += __shfl_xor(v, o);
    float rstd = rsqrtf(v * (1.f / 128.f) + 1e-6f);
    const float2 sv = *(const float2*)&scale[d2];
    const float2 bv = *(const float2*)&beta[d2];
    float2 o2;
    o2.x = d0 * rstd * sv.x + bv.x;
    o2.y = d1 * rstd * sv.y + bv.y;
    *(float2*)&out[(size_t)node * 128 + d2] = o2;
}

extern "C" void kernel_launch(void* const* d_in, const int* in_sizes, int n_in,
                              void* d_out, int out_size, void* d_ws, size_t ws_size,
                              hipStream_t stream) {
    const float* nf = (const float*)d_in[0];
    const int* fei = (const int*)d_in[1];
    const float* few = (const float*)d_in[2];
    const int* pei = (const int*)d_in[3];
    const float* pew = (const float*)d_in[4];
    const float* alpha = (const float*)d_in[5];
    const float* ip_w = (const float*)d_in[6];
    const float* ip_b = (const float*)d_in[7];
    const float* gf_wsrc = (const float*)d_in[8];
    const float* gf_wdst = (const float*)d_in[9];
    const float* gf_wedge = (const float*)d_in[10];
    const float* gf_attn = (const float*)d_in[11];
    const float* gf_bias = (const float*)d_in[12];
    const float* gp_wsrc = (const float*)d_in[13];
    const float* gp_wdst = (const float*)d_in[14];
    const float* gp_wedge = (const float*)d_in[15];
    const float* gp_attn = (const float*)d_in[16];
    const float* gp_bias = (const float*)d_in[17];
    const float* ln_scale = (const float*)d_in[18];
    const float* ln_bias = (const float*)d_in[19];

    const int N = in_sizes[0] / N_GENES;
    const int Ef = in_sizes[1] / 2;
    const int Ep = in_sizes[3] / 2;
    const int Etot = Ef + Ep;
    const int n2 = 2 * N;

    char* base = (char*)d_ws;
    size_t off = 0;
    auto carve = [&](size_t bytes) -> char* {
        char* p = base + off;
        off = (off + bytes + 255) & ~(size_t)255;
        return p;
    };
    unsigned short* Bt1 = (unsigned short*)carve((size_t)128 * 2048 * 2);
    unsigned short* Bf = (unsigned short*)carve(256 * 128 * 2);
    unsigned short* Bp = (unsigned short*)carve(256 * 128 * 2);
    unsigned short* hshd_f = (unsigned short*)carve((size_t)N * 256 * 2);
    unsigned short* hshd_p = (unsigned short*)carve((size_t)N * 256 * 2);
    float* h_full = (float*)carve((size_t)N * 128 * 4);
    int* deg = (int*)carve((size_t)n2 * 4);
    int* offs = (int*)carve((size_t)n2 * 4);
    int* cur = (int*)carve((size_t)n2 * 4);
    unsigned int* counter = (unsigned int*)carve(4);
    int2* srcw = (int2*)carve((size_t)Etot * 8);
    float* out_f = (float*)d_out;

    const int* src_f = fei;
    const int* dst_f = fei + Ef;
    const int* src_p = pei;
    const int* dst_p = pei + Ep;

    prep<<<(128 * 2048 + 2 * 256 * 128 + 255) / 256, 256, 0, stream>>>(
        ip_w, gf_wsrc, gf_wdst, gp_wsrc, gp_wdst, Bt1, Bf, Bp, deg, counter, n2);

    int gb1 = (N + 63) / 64;
    int degb = (Etot + 255) / 256;
    gemm_deg<<<gb1 + degb, 256, 0, stream>>>(nf, Bt1, ip_b, Bf, Bp, hshd_f, hshd_p,
                                             N, N_GENES, gb1,
                                             dst_f, Ef, dst_p, Ep, deg, N);

    seg_assign<<<(n2 + 255) / 256, 256, 0, stream>>>(deg, offs, cur, counter, n2);

    fill2<<<(Etot + 255) / 256, 256, 0, stream>>>(src_f, dst_f, few, Ef, src_p, dst_p, pew, Ep,
                                                  cur, srcw, N);

    gat2<<<(n2 + 3) / 4, 256, 0, stream>>>(offs, deg, srcw, hshd_f, hshd_p,
                                           gf_wedge, gf_attn, gf_bias,
                                           gp_wedge, gp_attn, gp_bias,
                                           h_full, out_f, N);

    final_kernel<<<(N + 3) / 4, 256, 0, stream>>>(h_full, out_f, alpha, ln_scale, ln_bias, N);
    (void)ws_size; (void)n_in; (void)out_size;
}

// Round 7
// 802.083 us; speedup vs baseline: 1.0359x; 1.0270x over previous
//
#include <hip/hip_runtime.h>
#include <hip/hip_bf16.h>

#define N_GENES 2000
#define SA 72
#define SH 136

typedef __attribute__((ext_vector_type(8))) short frag8;
typedef __attribute__((ext_vector_type(4))) float facc4;

static __device__ __forceinline__ unsigned short f2bf(float f) {
    unsigned int u = __float_as_uint(f);
    unsigned int r = (u + 0x7FFFu + ((u >> 16) & 1u)) >> 16;
    return (unsigned short)r;
}
static __device__ __forceinline__ ushort2 pk2(float a, float b) {
    __hip_bfloat162 r = __float22bfloat162_rn(float2{a, b});
    return *(ushort2*)&r;
}

// ---- weight transposes + deg/counter zeroing ----
__global__ void prep(const float* __restrict__ ip_w,
                     const float* __restrict__ ws_f, const float* __restrict__ wd_f,
                     const float* __restrict__ ws_p, const float* __restrict__ wd_p,
                     unsigned short* __restrict__ Bt1,
                     unsigned short* __restrict__ Bf, unsigned short* __restrict__ Bp,
                     int* __restrict__ deg, unsigned int* __restrict__ counter, int n2) {
    int idx = blockIdx.x * blockDim.x + threadIdx.x;
    if (idx < n2) deg[idx] = 0;
    if (idx == 0) counter[0] = 0u;
    if (idx < 128 * 2048) {
        int nrow = idx >> 11, k = idx & 2047;
        unsigned short v = 0;
        if (k < N_GENES) v = f2bf(ip_w[(size_t)k * 128 + nrow]);
        Bt1[idx] = v;
    } else {
        int q = idx - 128 * 2048;
        if (q >= 2 * 256 * 128) return;
        int g = q >> 15;
        int r = (q >> 7) & 255;
        int k = q & 127;
        const float* w = (g == 0) ? (r < 128 ? ws_f : wd_f) : (r < 128 ? ws_p : wd_p);
        (g == 0 ? Bf : Bp)[(r << 7) | k] = f2bf(w[k * 128 + (r & 127)]);
    }
}

// ---- mega dispatch: blocks [0,gemmBlocks) run the fused GEMM;
//      blocks [gemmBlocks,..) run the degree histogram (hidden under the GEMM). ----
__global__ __launch_bounds__(256) void gemm_deg(const float* __restrict__ A,
                                                const unsigned short* __restrict__ Bt,
                                                const float* __restrict__ bias,
                                                const unsigned short* __restrict__ Bf,
                                                const unsigned short* __restrict__ Bp,
                                                unsigned short* __restrict__ Cf,
                                                unsigned short* __restrict__ Cp,
                                                int M, int K, int gemmBlocks,
                                                const int* __restrict__ dst_f, int Ef,
                                                const int* __restrict__ dst_p, int Ep,
                                                int* __restrict__ deg, int N) {
    if (blockIdx.x >= gemmBlocks) {
        int e = (blockIdx.x - gemmBlocks) * 256 + threadIdx.x;
        if (e < Ef) atomicAdd(&deg[dst_f[e]], 1);
        else if (e < Ef + Ep) atomicAdd(&deg[N + dst_p[e - Ef]], 1);
        return;
    }
    const int Kpad = 2048;
    __shared__ __align__(16) unsigned short lA[64 * SA];
    __shared__ __align__(16) unsigned short lH[64 * SH];
    int t = threadIdx.x, lane = t & 63, wv = t >> 6;
    int lr = lane & 15, lq = lane >> 4;
    facc4 acc[4][2];
#pragma unroll
    for (int i = 0; i < 4; i++)
#pragma unroll
        for (int j = 0; j < 2; j++) acc[i][j] = (facc4){0.f, 0.f, 0.f, 0.f};
    int row_base = blockIdx.x * 64;

    int ar_r[4], ar_c[4];
    const float* ar_p[4];
#pragma unroll
    for (int j = 0; j < 4; j++) {
        int q = j * 256 + t;
        ar_r[j] = q >> 4;
        ar_c[j] = (q & 15) * 4;
        int rg = row_base + ar_r[j];
        if (rg >= M) rg = M - 1;
        ar_p[j] = A + (size_t)rg * K + ar_c[j];
    }
    const unsigned short* bp[4];
#pragma unroll
    for (int ks = 0; ks < 2; ks++)
#pragma unroll
        for (int ni = 0; ni < 2; ni++) {
            int col = wv * 32 + ni * 16 + lr;
            bp[ks * 2 + ni] = Bt + (size_t)col * Kpad + ks * 32 + lq * 8;
        }

    float4 ar[4];
    frag8 bfr[4];
#pragma unroll
    for (int j = 0; j < 4; j++) ar[j] = *(const float4*)(ar_p[j]);
#pragma unroll
    for (int f = 0; f < 4; f++) bfr[f] = *(const frag8*)(bp[f]);

    for (int k0 = 0; k0 < Kpad; k0 += 64) {
        __syncthreads();
#pragma unroll
        for (int j = 0; j < 4; j++) {
            ushort2 u01 = pk2(ar[j].x, ar[j].y);
            ushort2 u23 = pk2(ar[j].z, ar[j].w);
            ushort4 u = {u01.x, u01.y, u23.x, u23.y};
            *(ushort4*)&lA[ar_r[j] * SA + ar_c[j]] = u;
        }
        __syncthreads();
        int kn = k0 + 64;
        frag8 bfn[4];
        if (kn < Kpad) {
#pragma unroll
            for (int j = 0; j < 4; j++) {
                int kk = kn + ar_c[j];
                float4 v = {0.f, 0.f, 0.f, 0.f};
                if (kk < K) v = *(const float4*)(ar_p[j] + kn);
                ar[j] = v;
            }
#pragma unroll
            for (int f = 0; f < 4; f++) bfn[f] = *(const frag8*)(bp[f] + kn);
        }
#pragma unroll
        for (int ks = 0; ks < 2; ks++) {
            frag8 af[4];
#pragma unroll
            for (int mi = 0; mi < 4; mi++)
                af[mi] = *(const frag8*)&lA[(mi * 16 + lr) * SA + ks * 32 + lq * 8];
#pragma unroll
            for (int mi = 0; mi < 4; mi++)
#pragma unroll
                for (int ni = 0; ni < 2; ni++)
                    acc[mi][ni] = __builtin_amdgcn_mfma_f32_16x16x32_bf16(af[mi], bfr[ks * 2 + ni], acc[mi][ni], 0, 0, 0);
        }
        if (kn < Kpad) {
#pragma unroll
            for (int f = 0; f < 4; f++) bfr[f] = bfn[f];
        }
    }
    __syncthreads();
#pragma unroll
    for (int mi = 0; mi < 4; mi++) {
#pragma unroll
        for (int r = 0; r < 4; r++) {
            int row = mi * 16 + lq * 4 + r;
#pragma unroll
            for (int ni = 0; ni < 2; ni++) {
                int col = wv * 32 + ni * 16 + lr;
                lH[row * SH + col] = f2bf(acc[mi][ni][r] + bias[col]);
            }
        }
    }
    __syncthreads();
#pragma unroll 1
    for (int g = 0; g < 2; g++) {
        const unsigned short* B2 = g ? Bp : Bf;
        unsigned short* Cb = g ? Cp : Cf;
        facc4 a2[4][4];
#pragma unroll
        for (int i = 0; i < 4; i++)
#pragma unroll
            for (int j = 0; j < 4; j++) a2[i][j] = (facc4){0.f, 0.f, 0.f, 0.f};
#pragma unroll
        for (int ks = 0; ks < 4; ks++) {
            frag8 af[4], bf[4];
#pragma unroll
            for (int mi = 0; mi < 4; mi++)
                af[mi] = *(const frag8*)&lH[(mi * 16 + lr) * SH + ks * 32 + lq * 8];
#pragma unroll
            for (int ni = 0; ni < 4; ni++)
                bf[ni] = *(const frag8*)(B2 + ((wv * 64 + ni * 16 + lr) << 7) + ks * 32 + lq * 8);
#pragma unroll
            for (int mi = 0; mi < 4; mi++)
#pragma unroll
                for (int ni = 0; ni < 4; ni++)
                    a2[mi][ni] = __builtin_amdgcn_mfma_f32_16x16x32_bf16(af[mi], bf[ni], a2[mi][ni], 0, 0, 0);
        }
#pragma unroll
        for (int mi = 0; mi < 4; mi++) {
#pragma unroll
            for (int r = 0; r < 4; r++) {
                int row = row_base + mi * 16 + lq * 4 + r;
                if (row < M) {
#pragma unroll
                    for (int ni = 0; ni < 4; ni++) {
                        int col = wv * 64 + ni * 16 + lr;
                        Cb[(size_t)row * 256 + col] = f2bf(a2[mi][ni][r]);
                    }
                }
            }
        }
    }
}

// ---- unordered segment assignment; ONE atomic per block (wave totals via LDS) ----
__global__ __launch_bounds__(256) void seg_assign(const int* __restrict__ deg,
                                                  int* __restrict__ offs,
                                                  int* __restrict__ cur,
                                                  unsigned int* __restrict__ counter, int n2) {
    __shared__ int wbase[4];
    int t = threadIdx.x;
    int i = blockIdx.x * 256 + t;
    int lane = t & 63, wv = t >> 6;
    int c = (i < n2) ? deg[i] : 0;
    int incl = c;
#pragma unroll
    for (int o = 1; o < 64; o <<= 1) {
        int y = __shfl_up(incl, o);
        if (lane >= o) incl += y;
    }
    if (lane == 63) wbase[wv] = incl;
    __syncthreads();
    if (t == 0) {
        int s0 = wbase[0], s1 = wbase[1], s2 = wbase[2], s3 = wbase[3];
        int b = (int)atomicAdd(counter, (unsigned int)(s0 + s1 + s2 + s3));
        wbase[0] = b;
        wbase[1] = b + s0;
        wbase[2] = b + s0 + s1;
        wbase[3] = b + s0 + s1 + s2;
    }
    __syncthreads();
    int start = wbase[wv] + incl - c;
    if (i < n2) { offs[i] = start; cur[i] = start; }
}

// ---- fill CSR-ordered (src, weight) int2 pairs via per-node cursor ----
__global__ void fill2(const int* __restrict__ src_f, const int* __restrict__ dst_f,
                      const float* __restrict__ ew_f, int Ef,
                      const int* __restrict__ src_p, const int* __restrict__ dst_p,
                      const float* __restrict__ ew_p, int Ep,
                      int* __restrict__ cur, int2* __restrict__ srcw, int N) {
    int e = blockIdx.x * blockDim.x + threadIdx.x;
    if (e >= Ef + Ep) return;
    int g = (e >= Ef);
    int ee = g ? e - Ef : e;
    int d = g ? dst_p[ee] : dst_f[ee];
    int node = g ? N + d : d;
    int p = atomicAdd(&cur[node], 1);
    int s = g ? src_p[ee] : src_f[ee];
    float w = g ? ew_p[ee] : ew_f[ee];
    srcw[p] = make_int2(s, __float_as_int(w));
}

// ---- GAT: TWO nodes per wave (lanes 0-31 / 32-63), 4 dims/lane, head = 8-lane group.
//      Wave-wide shuffles/exps serve both edge streams; per-lane validity predication
//      handles degree mismatch exactly (zeroed p; rescale cancels in acc/l). ----
__global__ __launch_bounds__(256) void gat2(const int* __restrict__ offs,
                                            const int* __restrict__ deg,
                                            const int2* __restrict__ srcw,
                                            const unsigned short* __restrict__ hshd_f,
                                            const unsigned short* __restrict__ hshd_p,
                                            const float* __restrict__ wedge_f,
                                            const float* __restrict__ attn_f,
                                            const float* __restrict__ bias_f,
                                            const float* __restrict__ wedge_p,
                                            const float* __restrict__ attn_p,
                                            const float* __restrict__ bias_p,
                                            float* __restrict__ out_full,
                                            float* __restrict__ out_pruned, int N) {
    int wid = blockIdx.x * 4 + (threadIdx.x >> 6);
    if (wid * 2 >= 2 * N) return;
    int lane = threadIdx.x & 63;
    int half = lane >> 5;
    int wl = lane & 31;
    int node = wid * 2 + half;          // 2N even -> never OOB
    int g = node >= N;
    int onode = g ? node - N : node;
    const unsigned short* hshd = g ? hshd_p : hshd_f;
    const float* wedge = g ? wedge_p : wedge_f;
    const float* attn = g ? attn_p : attn_f;
    const float* bias = g ? bias_p : bias_f;
    float* out = g ? out_pruned : out_full;
    int d4 = wl * 4;
    const float LOG2E = 1.4426950408889634f;
    float4 wv4 = *(const float4*)&wedge[d4];
    float4 av4 = *(const float4*)&attn[d4];
    av4.x *= LOG2E; av4.y *= LOG2E; av4.z *= LOG2E; av4.w *= LOG2E;
    uint2 hdr = *(const uint2*)&hshd[(size_t)onode * 256 + 128 + d4];
    const float hd0 = __uint_as_float(hdr.x << 16);
    const float hd1 = __uint_as_float(hdr.x & 0xffff0000u);
    const float hd2 = __uint_as_float(hdr.y << 16);
    const float hd3 = __uint_as_float(hdr.y & 0xffff0000u);
    int s = offs[node], cnt = deg[node];
    if (cnt <= 0) s = 0;                 // any valid address; contributions predicated off
    int mc = max(cnt, __shfl_xor(cnt, 32));   // wave-uniform loop bound
    float m = -INFINITY, l = 0.f;
    float a0 = 0.f, a1 = 0.f, a2 = 0.f, a3 = 0.f;
    if (mc > 0) {
        int last = s + (cnt > 0 ? cnt : 1) - 1;
        auto CL = [last](int j) { return j > last ? last : j; };
        int2 e0 = srcw[CL(s)], e1 = srcw[CL(s + 1)], e2 = srcw[CL(s + 2)], e3 = srcw[CL(s + 3)];
        int2 e4 = srcw[CL(s + 4)], e5 = srcw[CL(s + 5)];
        uint2 hr0 = *(const uint2*)&hshd[(size_t)e0.x * 256 + d4];
        uint2 hr1 = *(const uint2*)&hshd[(size_t)e1.x * 256 + d4];
        uint2 hr2 = *(const uint2*)&hshd[(size_t)e2.x * 256 + d4];
        uint2 hr3 = *(const uint2*)&hshd[(size_t)e3.x * 256 + d4];
        for (int i = 0; i < mc; i += 2) {
            int2 ea = srcw[CL(s + i + 6)], eb = srcw[CL(s + i + 7)];
            uint2 hr4 = *(const uint2*)&hshd[(size_t)e4.x * 256 + d4];
            uint2 hr5 = *(const uint2*)&hshd[(size_t)e5.x * 256 + d4];
            {
                float h0 = __uint_as_float(hr0.x << 16);
                float h1 = __uint_as_float(hr0.x & 0xffff0000u);
                float h2 = __uint_as_float(hr0.y << 16);
                float h3 = __uint_as_float(hr0.y & 0xffff0000u);
                float w = __int_as_float(e0.y);
                float z0 = fmaf(w, wv4.x, h0 + hd0); z0 = (z0 > 0.f) ? z0 : 0.2f * z0;
                float z1 = fmaf(w, wv4.y, h1 + hd1); z1 = (z1 > 0.f) ? z1 : 0.2f * z1;
                float z2 = fmaf(w, wv4.z, h2 + hd2); z2 = (z2 > 0.f) ? z2 : 0.2f * z2;
                float z3 = fmaf(w, wv4.w, h3 + hd3); z3 = (z3 > 0.f) ? z3 : 0.2f * z3;
                float t = fmaf(z3, av4.w, fmaf(z2, av4.z, fmaf(z1, av4.y, z0 * av4.x)));
                t += __shfl_xor(t, 1);
                t += __shfl_xor(t, 2);
                t += __shfl_xor(t, 4);
                float mn = fmaxf(m, t);
                float sc = __builtin_amdgcn_exp2f(m - mn);
                float p = __builtin_amdgcn_exp2f(t - mn);
                p = (i < cnt) ? p : 0.f;
                l = l * sc + p;
                a0 = fmaf(p, h0, a0 * sc);
                a1 = fmaf(p, h1, a1 * sc);
                a2 = fmaf(p, h2, a2 * sc);
                a3 = fmaf(p, h3, a3 * sc);
                m = mn;
            }
            {
                float h0 = __uint_as_float(hr1.x << 16);
                float h1 = __uint_as_float(hr1.x & 0xffff0000u);
                float h2 = __uint_as_float(hr1.y << 16);
                float h3 = __uint_as_float(hr1.y & 0xffff0000u);
                float w = __int_as_float(e1.y);
                float z0 = fmaf(w, wv4.x, h0 + hd0); z0 = (z0 > 0.f) ? z0 : 0.2f * z0;
                float z1 = fmaf(w, wv4.y, h1 + hd1); z1 = (z1 > 0.f) ? z1 : 0.2f * z1;
                float z2 = fmaf(w, wv4.z, h2 + hd2); z2 = (z2 > 0.f) ? z2 : 0.2f * z2;
                float z3 = fmaf(w, wv4.w, h3 + hd3); z3 = (z3 > 0.f) ? z3 : 0.2f * z3;
                float t = fmaf(z3, av4.w, fmaf(z2, av4.z, fmaf(z1, av4.y, z0 * av4.x)));
                t += __shfl_xor(t, 1);
                t += __shfl_xor(t, 2);
                t += __shfl_xor(t, 4);
                float mn = fmaxf(m, t);
                float sc = __builtin_amdgcn_exp2f(m - mn);
                float p = __builtin_amdgcn_exp2f(t - mn);
                p = (i + 1 < cnt) ? p : 0.f;
                l = l * sc + p;
                a0 = fmaf(p, h0, a0 * sc);
                a1 = fmaf(p, h1, a1 * sc);
                a2 = fmaf(p, h2, a2 * sc);
                a3 = fmaf(p, h3, a3 * sc);
                m = mn;
            }
            e0 = e2; e1 = e3; e2 = e4; e3 = e5; e4 = ea; e5 = eb;
            hr0 = hr2; hr1 = hr3; hr2 = hr4; hr3 = hr5;
        }
    }
    float inv = 1.f / (l + 1e-16f);
    const float4 bv = *(const float4*)&bias[d4];
    float4 o;
    o.x = fmaf(a0, inv, bv.x);
    o.y = fmaf(a1, inv, bv.y);
    o.z = fmaf(a2, inv, bv.z);
    o.w = fmaf(a3, inv, bv.w);
    *(float4*)&out[(size_t)onode * 128 + d4] = o;
}

// ---- combine + ELU + LayerNorm (in-place on d_out holding h_pruned), 2 dims/lane ----
__global__ __launch_bounds__(256) void final_kernel(const float* __restrict__ hf,
                                                    float* __restrict__ out,
                                                    const float* __restrict__ alpha_p,
                                                    const float* __restrict__ scale,
                                                    const float* __restrict__ beta, int n) {
    int node = blockIdx.x * 4 + (threadIdx.x >> 6);
    if (node >= n) return;
    int lane = threadIdx.x & 63;
    int d2 = lane * 2;
    float a = *alpha_p;
    float2 f = *(const float2*)&hf[(size_t)node * 128 + d2];
    float2 p = *(const float2*)&out[(size_t)node * 128 + d2];
    float x0 = (1.f - a) * f.x + a * p.x;
    float x1 = (1.f - a) * f.y + a * p.y;
    x0 = (x0 > 0.f) ? x0 : expm1f(x0);
    x1 = (x1 > 0.f) ? x1 : expm1f(x1);
    float sm = x0 + x1;
#pragma unroll
    for (int o = 32; o >= 1; o >>= 1) sm += __shfl_xor(sm, o);
    float mu = sm * (1.f / 128.f);
    float d0 = x0 - mu, d1 = x1 - mu;
    float v = d0 * d0 + d1 * d1;
#pragma unroll
    for (int o = 32; o >= 1; o >>= 1) v += __shfl_xor(v, o);
    float rstd = rsqrtf(v * (1.f / 128.f) + 1e-6f);
    const float2 sv = *(const float2*)&scale[d2];
    const float2 bv = *(const float2*)&beta[d2];
    float2 o2;
    o2.x = d0 * rstd * sv.x + bv.x;
    o2.y = d1 * rstd * sv.y + bv.y;
    *(float2*)&out[(size_t)node * 128 + d2] = o2;
}

extern "C" void kernel_launch(void* const* d_in, const int* in_sizes, int n_in,
                              void* d_out, int out_size, void* d_ws, size_t ws_size,
                              hipStream_t stream) {
    const float* nf = (const float*)d_in[0];
    const int* fei = (const int*)d_in[1];
    const float* few = (const float*)d_in[2];
    const int* pei = (const int*)d_in[3];
    const float* pew = (const float*)d_in[4];
    const float* alpha = (const float*)d_in[5];
    const float* ip_w = (const float*)d_in[6];
    const float* ip_b = (const float*)d_in[7];
    const float* gf_wsrc = (const float*)d_in[8];
    const float* gf_wdst = (const float*)d_in[9];
    const float* gf_wedge = (const float*)d_in[10];
    const float* gf_attn = (const float*)d_in[11];
    const float* gf_bias = (const float*)d_in[12];
    const float* gp_wsrc = (const float*)d_in[13];
    const float* gp_wdst = (const float*)d_in[14];
    const float* gp_wedge = (const float*)d_in[15];
    const float* gp_attn = (const float*)d_in[16];
    const float* gp_bias = (const float*)d_in[17];
    const float* ln_scale = (const float*)d_in[18];
    const float* ln_bias = (const float*)d_in[19];

    const int N = in_sizes[0] / N_GENES;
    const int Ef = in_sizes[1] / 2;
    const int Ep = in_sizes[3] / 2;
    const int Etot = Ef + Ep;
    const int n2 = 2 * N;

    char* base = (char*)d_ws;
    size_t off = 0;
    auto carve = [&](size_t bytes) -> char* {
        char* p = base + off;
        off = (off + bytes + 255) & ~(size_t)255;
        return p;
    };
    unsigned short* Bt1 = (unsigned short*)carve((size_t)128 * 2048 * 2);
    unsigned short* Bf = (unsigned short*)carve(256 * 128 * 2);
    unsigned short* Bp = (unsigned short*)carve(256 * 128 * 2);
    unsigned short* hshd_f = (unsigned short*)carve((size_t)N * 256 * 2);
    unsigned short* hshd_p = (unsigned short*)carve((size_t)N * 256 * 2);
    float* h_full = (float*)carve((size_t)N * 128 * 4);
    int* deg = (int*)carve((size_t)n2 * 4);
    int* offs = (int*)carve((size_t)n2 * 4);
    int* cur = (int*)carve((size_t)n2 * 4);
    unsigned int* counter = (unsigned int*)carve(4);
    int2* srcw = (int2*)carve((size_t)Etot * 8);
    float* out_f = (float*)d_out;

    const int* src_f = fei;
    const int* dst_f = fei + Ef;
    const int* src_p = pei;
    const int* dst_p = pei + Ep;

    prep<<<(128 * 2048 + 2 * 256 * 128 + 255) / 256, 256, 0, stream>>>(
        ip_w, gf_wsrc, gf_wdst, gp_wsrc, gp_wdst, Bt1, Bf, Bp, deg, counter, n2);

    int gb1 = (N + 63) / 64;
    int degb = (Etot + 255) / 256;
    gemm_deg<<<gb1 + degb, 256, 0, stream>>>(nf, Bt1, ip_b, Bf, Bp, hshd_f, hshd_p,
                                             N, N_GENES, gb1,
                                             dst_f, Ef, dst_p, Ep, deg, N);

    seg_assign<<<(n2 + 255) / 256, 256, 0, stream>>>(deg, offs, cur, counter, n2);

    fill2<<<(Etot + 255) / 256, 256, 0, stream>>>(src_f, dst_f, few, Ef, src_p, dst_p, pew, Ep,
                                                  cur, srcw, N);

    int gwaves = (n2 + 1) / 2;
    gat2<<<(gwaves + 3) / 4, 256, 0, stream>>>(offs, deg, srcw, hshd_f, hshd_p,
                                               gf_wedge, gf_attn, gf_bias,
                                               gp_wedge, gp_attn, gp_bias,
                                               h_full, out_f, N);

    final_kernel<<<(N + 3) / 4, 256, 0, stream>>>(h_full, out_f, alpha, ln_scale, ln_bias, N);
    (void)ws_size; (void)n_in; (void)out_size;
}

// Round 8
// 783.132 us; speedup vs baseline: 1.0610x; 1.0242x over previous
//
#include <hip/hip_runtime.h>
#include <hip/hip_bf16.h>

#define N_GENES 2000
#define SA 72
#define SH 136

typedef __attribute__((ext_vector_type(8))) short frag8;
typedef __attribute__((ext_vector_type(4))) float facc4;

static __device__ __forceinline__ unsigned short f2bf(float f) {
    unsigned int u = __float_as_uint(f);
    unsigned int r = (u + 0x7FFFu + ((u >> 16) & 1u)) >> 16;
    return (unsigned short)r;
}
static __device__ __forceinline__ ushort2 pk2(float a, float b) {
    __hip_bfloat162 r = __float22bfloat162_rn(float2{a, b});
    return *(ushort2*)&r;
}

// ---- weight transposes + degree histogram (deg work overlaps transpose blocks) ----
__global__ void prep_deg(const float* __restrict__ ip_w,
                         const float* __restrict__ ws_f, const float* __restrict__ wd_f,
                         const float* __restrict__ ws_p, const float* __restrict__ wd_p,
                         unsigned short* __restrict__ Bt1,
                         unsigned short* __restrict__ Bf, unsigned short* __restrict__ Bp,
                         const int* __restrict__ dst_f, int Ef,
                         const int* __restrict__ dst_p, int Ep,
                         int* __restrict__ deg, int N) {
    int idx = blockIdx.x * blockDim.x + threadIdx.x;
    if (idx < 128 * 2048) {
        int nrow = idx >> 11, k = idx & 2047;
        unsigned short v = 0;
        if (k < N_GENES) v = f2bf(ip_w[(size_t)k * 128 + nrow]);
        Bt1[idx] = v;
    } else if (idx < 128 * 2048 + 2 * 256 * 128) {
        int q = idx - 128 * 2048;
        int g = q >> 15;
        int r = (q >> 7) & 255;
        int k = q & 127;
        const float* w = (g == 0) ? (r < 128 ? ws_f : wd_f) : (r < 128 ? ws_p : wd_p);
        (g == 0 ? Bf : Bp)[(r << 7) | k] = f2bf(w[k * 128 + (r & 127)]);
    } else {
        int e = idx - (128 * 2048 + 2 * 256 * 128);
        if (e < Ef) atomicAdd(&deg[dst_f[e]], 1);
        else if (e < Ef + Ep) atomicAdd(&deg[N + dst_p[e - Ef]], 1);
    }
}

// ---- unordered segment assignment; ONE atomic per block (wave totals via LDS) ----
__global__ __launch_bounds__(256) void seg_assign(const int* __restrict__ deg,
                                                  int* __restrict__ offs,
                                                  int* __restrict__ cur,
                                                  unsigned int* __restrict__ counter, int n2) {
    __shared__ int wbase[4];
    int t = threadIdx.x;
    int i = blockIdx.x * 256 + t;
    int lane = t & 63, wv = t >> 6;
    int c = (i < n2) ? deg[i] : 0;
    int incl = c;
#pragma unroll
    for (int o = 1; o < 64; o <<= 1) {
        int y = __shfl_up(incl, o);
        if (lane >= o) incl += y;
    }
    if (lane == 63) wbase[wv] = incl;
    __syncthreads();
    if (t == 0) {
        int s0 = wbase[0], s1 = wbase[1], s2 = wbase[2], s3 = wbase[3];
        int b = (int)atomicAdd(counter, (unsigned int)(s0 + s1 + s2 + s3));
        wbase[0] = b;
        wbase[1] = b + s0;
        wbase[2] = b + s0 + s1;
        wbase[3] = b + s0 + s1 + s2;
    }
    __syncthreads();
    int start = wbase[wv] + incl - c;
    if (i < n2) { offs[i] = start; cur[i] = start; }
}

// ---- mega dispatch: blocks [0,gemmBlocks) run the fused GEMM;
//      blocks [gemmBlocks,..) run fill2 (CSR scatter, hidden under the GEMM). ----
__global__ __launch_bounds__(256) void gemm_fill(const float* __restrict__ A,
                                                 const unsigned short* __restrict__ Bt,
                                                 const float* __restrict__ bias,
                                                 const unsigned short* __restrict__ Bf,
                                                 const unsigned short* __restrict__ Bp,
                                                 unsigned short* __restrict__ Cf,
                                                 unsigned short* __restrict__ Cp,
                                                 int M, int K, int gemmBlocks,
                                                 const int* __restrict__ src_f,
                                                 const int* __restrict__ dst_f,
                                                 const float* __restrict__ ew_f, int Ef,
                                                 const int* __restrict__ src_p,
                                                 const int* __restrict__ dst_p,
                                                 const float* __restrict__ ew_p, int Ep,
                                                 int* __restrict__ cur,
                                                 int2* __restrict__ srcw, int N) {
    if (blockIdx.x >= gemmBlocks) {
        int e = (blockIdx.x - gemmBlocks) * 256 + threadIdx.x;
        if (e >= Ef + Ep) return;
        int g = (e >= Ef);
        int ee = g ? e - Ef : e;
        int d = g ? dst_p[ee] : dst_f[ee];
        int node = g ? N + d : d;
        int p = atomicAdd(&cur[node], 1);
        int s = g ? src_p[ee] : src_f[ee];
        float w = g ? ew_p[ee] : ew_f[ee];
        srcw[p] = make_int2(s, __float_as_int(w));
        return;
    }
    const int Kpad = 2048;
    __shared__ __align__(16) unsigned short lA[64 * SA];
    __shared__ __align__(16) unsigned short lH[64 * SH];
    int t = threadIdx.x, lane = t & 63, wv = t >> 6;
    int lr = lane & 15, lq = lane >> 4;
    facc4 acc[4][2];
#pragma unroll
    for (int i = 0; i < 4; i++)
#pragma unroll
        for (int j = 0; j < 2; j++) acc[i][j] = (facc4){0.f, 0.f, 0.f, 0.f};
    int row_base = blockIdx.x * 64;

    int ar_r[4], ar_c[4];
    const float* ar_p[4];
#pragma unroll
    for (int j = 0; j < 4; j++) {
        int q = j * 256 + t;
        ar_r[j] = q >> 4;
        ar_c[j] = (q & 15) * 4;
        int rg = row_base + ar_r[j];
        if (rg >= M) rg = M - 1;
        ar_p[j] = A + (size_t)rg * K + ar_c[j];
    }
    const unsigned short* bp[4];
#pragma unroll
    for (int ks = 0; ks < 2; ks++)
#pragma unroll
        for (int ni = 0; ni < 2; ni++) {
            int col = wv * 32 + ni * 16 + lr;
            bp[ks * 2 + ni] = Bt + (size_t)col * Kpad + ks * 32 + lq * 8;
        }

    float4 ar[4];
    frag8 bfr[4];
#pragma unroll
    for (int j = 0; j < 4; j++) ar[j] = *(const float4*)(ar_p[j]);
#pragma unroll
    for (int f = 0; f < 4; f++) bfr[f] = *(const frag8*)(bp[f]);

    for (int k0 = 0; k0 < Kpad; k0 += 64) {
        __syncthreads();
#pragma unroll
        for (int j = 0; j < 4; j++) {
            ushort2 u01 = pk2(ar[j].x, ar[j].y);
            ushort2 u23 = pk2(ar[j].z, ar[j].w);
            ushort4 u = {u01.x, u01.y, u23.x, u23.y};
            *(ushort4*)&lA[ar_r[j] * SA + ar_c[j]] = u;
        }
        __syncthreads();
        int kn = k0 + 64;
        frag8 bfn[4];
        if (kn < Kpad) {
#pragma unroll
            for (int j = 0; j < 4; j++) {
                int kk = kn + ar_c[j];
                float4 v = {0.f, 0.f, 0.f, 0.f};
                if (kk < K) v = *(const float4*)(ar_p[j] + kn);
                ar[j] = v;
            }
#pragma unroll
            for (int f = 0; f < 4; f++) bfn[f] = *(const frag8*)(bp[f] + kn);
        }
#pragma unroll
        for (int ks = 0; ks < 2; ks++) {
            frag8 af[4];
#pragma unroll
            for (int mi = 0; mi < 4; mi++)
                af[mi] = *(const frag8*)&lA[(mi * 16 + lr) * SA + ks * 32 + lq * 8];
#pragma unroll
            for (int mi = 0; mi < 4; mi++)
#pragma unroll
                for (int ni = 0; ni < 2; ni++)
                    acc[mi][ni] = __builtin_amdgcn_mfma_f32_16x16x32_bf16(af[mi], bfr[ks * 2 + ni], acc[mi][ni], 0, 0, 0);
        }
        if (kn < Kpad) {
#pragma unroll
            for (int f = 0; f < 4; f++) bfr[f] = bfn[f];
        }
    }
    __syncthreads();
#pragma unroll
    for (int mi = 0; mi < 4; mi++) {
#pragma unroll
        for (int r = 0; r < 4; r++) {
            int row = mi * 16 + lq * 4 + r;
#pragma unroll
            for (int ni = 0; ni < 2; ni++) {
                int col = wv * 32 + ni * 16 + lr;
                lH[row * SH + col] = f2bf(acc[mi][ni][r] + bias[col]);
            }
        }
    }
    __syncthreads();
#pragma unroll 1
    for (int g = 0; g < 2; g++) {
        const unsigned short* B2 = g ? Bp : Bf;
        unsigned short* Cb = g ? Cp : Cf;
        facc4 a2[4][4];
#pragma unroll
        for (int i = 0; i < 4; i++)
#pragma unroll
            for (int j = 0; j < 4; j++) a2[i][j] = (facc4){0.f, 0.f, 0.f, 0.f};
#pragma unroll
        for (int ks = 0; ks < 4; ks++) {
            frag8 af[4], bf[4];
#pragma unroll
            for (int mi = 0; mi < 4; mi++)
                af[mi] = *(const frag8*)&lH[(mi * 16 + lr) * SH + ks * 32 + lq * 8];
#pragma unroll
            for (int ni = 0; ni < 4; ni++)
                bf[ni] = *(const frag8*)(B2 + ((wv * 64 + ni * 16 + lr) << 7) + ks * 32 + lq * 8);
#pragma unroll
            for (int mi = 0; mi < 4; mi++)
#pragma unroll
                for (int ni = 0; ni < 4; ni++)
                    a2[mi][ni] = __builtin_amdgcn_mfma_f32_16x16x32_bf16(af[mi], bf[ni], a2[mi][ni], 0, 0, 0);
        }
#pragma unroll
        for (int mi = 0; mi < 4; mi++) {
#pragma unroll
            for (int r = 0; r < 4; r++) {
                int row = row_base + mi * 16 + lq * 4 + r;
                if (row < M) {
#pragma unroll
                    for (int ni = 0; ni < 4; ni++) {
                        int col = wv * 64 + ni * 16 + lr;
                        Cb[(size_t)row * 256 + col] = f2bf(a2[mi][ni][r]);
                    }
                }
            }
        }
    }
}

// ---- GAT: TWO nodes per wave (lanes 0-31 / 32-63), 4 dims/lane, head = 8-lane group ----
__global__ __launch_bounds__(256) void gat2(const int* __restrict__ offs,
                                            const int* __restrict__ deg,
                                            const int2* __restrict__ srcw,
                                            const unsigned short* __restrict__ hshd_f,
                                            const unsigned short* __restrict__ hshd_p,
                                            const float* __restrict__ wedge_f,
                                            const float* __restrict__ attn_f,
                                            const float* __restrict__ bias_f,
                                            const float* __restrict__ wedge_p,
                                            const float* __restrict__ attn_p,
                                            const float* __restrict__ bias_p,
                                            float* __restrict__ out_full,
                                            float* __restrict__ out_pruned, int N) {
    int wid = blockIdx.x * 4 + (threadIdx.x >> 6);
    if (wid * 2 >= 2 * N) return;
    int lane = threadIdx.x & 63;
    int half = lane >> 5;
    int wl = lane & 31;
    int node = wid * 2 + half;
    int g = node >= N;
    int onode = g ? node - N : node;
    const unsigned short* hshd = g ? hshd_p : hshd_f;
    const float* wedge = g ? wedge_p : wedge_f;
    const float* attn = g ? attn_p : attn_f;
    const float* bias = g ? bias_p : bias_f;
    float* out = g ? out_pruned : out_full;
    int d4 = wl * 4;
    const float LOG2E = 1.4426950408889634f;
    float4 wv4 = *(const float4*)&wedge[d4];
    float4 av4 = *(const float4*)&attn[d4];
    av4.x *= LOG2E; av4.y *= LOG2E; av4.z *= LOG2E; av4.w *= LOG2E;
    uint2 hdr = *(const uint2*)&hshd[(size_t)onode * 256 + 128 + d4];
    const float hd0 = __uint_as_float(hdr.x << 16);
    const float hd1 = __uint_as_float(hdr.x & 0xffff0000u);
    const float hd2 = __uint_as_float(hdr.y << 16);
    const float hd3 = __uint_as_float(hdr.y & 0xffff0000u);
    int s = offs[node], cnt = deg[node];
    if (cnt <= 0) s = 0;
    int mc = max(cnt, __shfl_xor(cnt, 32));
    float m = -INFINITY, l = 0.f;
    float a0 = 0.f, a1 = 0.f, a2 = 0.f, a3 = 0.f;
    if (mc > 0) {
        int last = s + (cnt > 0 ? cnt : 1) - 1;
        auto CL = [last](int j) { return j > last ? last : j; };
        int2 e0 = srcw[CL(s)], e1 = srcw[CL(s + 1)], e2 = srcw[CL(s + 2)], e3 = srcw[CL(s + 3)];
        int2 e4 = srcw[CL(s + 4)], e5 = srcw[CL(s + 5)];
        uint2 hr0 = *(const uint2*)&hshd[(size_t)e0.x * 256 + d4];
        uint2 hr1 = *(const uint2*)&hshd[(size_t)e1.x * 256 + d4];
        uint2 hr2 = *(const uint2*)&hshd[(size_t)e2.x * 256 + d4];
        uint2 hr3 = *(const uint2*)&hshd[(size_t)e3.x * 256 + d4];
        for (int i = 0; i < mc; i += 2) {
            int2 ea = srcw[CL(s + i + 6)], eb = srcw[CL(s + i + 7)];
            uint2 hr4 = *(const uint2*)&hshd[(size_t)e4.x * 256 + d4];
            uint2 hr5 = *(const uint2*)&hshd[(size_t)e5.x * 256 + d4];
            {
                float h0 = __uint_as_float(hr0.x << 16);
                float h1 = __uint_as_float(hr0.x & 0xffff0000u);
                float h2 = __uint_as_float(hr0.y << 16);
                float h3 = __uint_as_float(hr0.y & 0xffff0000u);
                float w = __int_as_float(e0.y);
                float z0 = fmaf(w, wv4.x, h0 + hd0); z0 = (z0 > 0.f) ? z0 : 0.2f * z0;
                float z1 = fmaf(w, wv4.y, h1 + hd1); z1 = (z1 > 0.f) ? z1 : 0.2f * z1;
                float z2 = fmaf(w, wv4.z, h2 + hd2); z2 = (z2 > 0.f) ? z2 : 0.2f * z2;
                float z3 = fmaf(w, wv4.w, h3 + hd3); z3 = (z3 > 0.f) ? z3 : 0.2f * z3;
                float t = fmaf(z3, av4.w, fmaf(z2, av4.z, fmaf(z1, av4.y, z0 * av4.x)));
                t += __shfl_xor(t, 1);
                t += __shfl_xor(t, 2);
                t += __shfl_xor(t, 4);
                float mn = fmaxf(m, t);
                float sc = __builtin_amdgcn_exp2f(m - mn);
                float p = __builtin_amdgcn_exp2f(t - mn);
                p = (i < cnt) ? p : 0.f;
                l = l * sc + p;
                a0 = fmaf(p, h0, a0 * sc);
                a1 = fmaf(p, h1, a1 * sc);
                a2 = fmaf(p, h2, a2 * sc);
                a3 = fmaf(p, h3, a3 * sc);
                m = mn;
            }
            {
                float h0 = __uint_as_float(hr1.x << 16);
                float h1 = __uint_as_float(hr1.x & 0xffff0000u);
                float h2 = __uint_as_float(hr1.y << 16);
                float h3 = __uint_as_float(hr1.y & 0xffff0000u);
                float w = __int_as_float(e1.y);
                float z0 = fmaf(w, wv4.x, h0 + hd0); z0 = (z0 > 0.f) ? z0 : 0.2f * z0;
                float z1 = fmaf(w, wv4.y, h1 + hd1); z1 = (z1 > 0.f) ? z1 : 0.2f * z1;
                float z2 = fmaf(w, wv4.z, h2 + hd2); z2 = (z2 > 0.f) ? z2 : 0.2f * z2;
                float z3 = fmaf(w, wv4.w, h3 + hd3); z3 = (z3 > 0.f) ? z3 : 0.2f * z3;
                float t = fmaf(z3, av4.w, fmaf(z2, av4.z, fmaf(z1, av4.y, z0 * av4.x)));
                t += __shfl_xor(t, 1);
                t += __shfl_xor(t, 2);
                t += __shfl_xor(t, 4);
                float mn = fmaxf(m, t);
                float sc = __builtin_amdgcn_exp2f(m - mn);
                float p = __builtin_amdgcn_exp2f(t - mn);
                p = (i + 1 < cnt) ? p : 0.f;
                l = l * sc + p;
                a0 = fmaf(p, h0, a0 * sc);
                a1 = fmaf(p, h1, a1 * sc);
                a2 = fmaf(p, h2, a2 * sc);
                a3 = fmaf(p, h3, a3 * sc);
                m = mn;
            }
            e0 = e2; e1 = e3; e2 = e4; e3 = e5; e4 = ea; e5 = eb;
            hr0 = hr2; hr1 = hr3; hr2 = hr4; hr3 = hr5;
        }
    }
    float inv = 1.f / (l + 1e-16f);
    const float4 bv = *(const float4*)&bias[d4];
    float4 o;
    o.x = fmaf(a0, inv, bv.x);
    o.y = fmaf(a1, inv, bv.y);
    o.z = fmaf(a2, inv, bv.z);
    o.w = fmaf(a3, inv, bv.w);
    *(float4*)&out[(size_t)onode * 128 + d4] = o;
}

// ---- combine + ELU + LayerNorm (in-place on d_out holding h_pruned), 2 dims/lane ----
__global__ __launch_bounds__(256) void final_kernel(const float* __restrict__ hf,
                                                    float* __restrict__ out,
                                                    const float* __restrict__ alpha_p,
                                                    const float* __restrict__ scale,
                                                    const float* __restrict__ beta, int n) {
    int node = blockIdx.x * 4 + (threadIdx.x >> 6);
    if (node >= n) return;
    int lane = threadIdx.x & 63;
    int d2 = lane * 2;
    float a = *alpha_p;
    float2 f = *(const float2*)&hf[(size_t)node * 128 + d2];
    float2 p = *(const float2*)&out[(size_t)node * 128 + d2];
    float x0 = (1.f - a) * f.x + a * p.x;
    float x1 = (1.f - a) * f.y + a * p.y;
    x0 = (x0 > 0.f) ? x0 : expm1f(x0);
    x1 = (x1 > 0.f) ? x1 : expm1f(x1);
    float sm = x0 + x1;
#pragma unroll
    for (int o = 32; o >= 1; o >>= 1) sm += __shfl_xor(sm, o);
    float mu = sm * (1.f / 128.f);
    float d0 = x0 - mu, d1 = x1 - mu;
    float v = d0 * d0 + d1 * d1;
#pragma unroll
    for (int o = 32; o >= 1; o >>= 1) v += __shfl_xor(v, o);
    float rstd = rsqrtf(v * (1.f / 128.f) + 1e-6f);
    const float2 sv = *(const float2*)&scale[d2];
    const float2 bv = *(const float2*)&beta[d2];
    float2 o2;
    o2.x = d0 * rstd * sv.x + bv.x;
    o2.y = d1 * rstd * sv.y + bv.y;
    *(float2*)&out[(size_t)node * 128 + d2] = o2;
}

extern "C" void kernel_launch(void* const* d_in, const int* in_sizes, int n_in,
                              void* d_out, int out_size, void* d_ws, size_t ws_size,
                              hipStream_t stream) {
    const float* nf = (const float*)d_in[0];
    const int* fei = (const int*)d_in[1];
    const float* few = (const float*)d_in[2];
    const int* pei = (const int*)d_in[3];
    const float* pew = (const float*)d_in[4];
    const float* alpha = (const float*)d_in[5];
    const float* ip_w = (const float*)d_in[6];
    const float* ip_b = (const float*)d_in[7];
    const float* gf_wsrc = (const float*)d_in[8];
    const float* gf_wdst = (const float*)d_in[9];
    const float* gf_wedge = (const float*)d_in[10];
    const float* gf_attn = (const float*)d_in[11];
    const float* gf_bias = (const float*)d_in[12];
    const float* gp_wsrc = (const float*)d_in[13];
    const float* gp_wdst = (const float*)d_in[14];
    const float* gp_wedge = (const float*)d_in[15];
    const float* gp_attn = (const float*)d_in[16];
    const float* gp_bias = (const float*)d_in[17];
    const float* ln_scale = (const float*)d_in[18];
    const float* ln_bias = (const float*)d_in[19];

    const int N = in_sizes[0] / N_GENES;
    const int Ef = in_sizes[1] / 2;
    const int Ep = in_sizes[3] / 2;
    const int Etot = Ef + Ep;
    const int n2 = 2 * N;

    char* base = (char*)d_ws;
    size_t off = 0;
    auto carve = [&](size_t bytes) -> char* {
        char* p = base + off;
        off = (off + bytes + 255) & ~(size_t)255;
        return p;
    };
    unsigned short* Bt1 = (unsigned short*)carve((size_t)128 * 2048 * 2);
    unsigned short* Bf = (unsigned short*)carve(256 * 128 * 2);
    unsigned short* Bp = (unsigned short*)carve(256 * 128 * 2);
    unsigned short* hshd_f = (unsigned short*)carve((size_t)N * 256 * 2);
    unsigned short* hshd_p = (unsigned short*)carve((size_t)N * 256 * 2);
    float* h_full = (float*)carve((size_t)N * 128 * 4);
    unsigned int* counter = (unsigned int*)carve(4);      // adjacent to deg: one memset covers both
    int* deg = (int*)carve((size_t)n2 * 4);
    int* offs = (int*)carve((size_t)n2 * 4);
    int* cur = (int*)carve((size_t)n2 * 4);
    int2* srcw = (int2*)carve((size_t)Etot * 8);
    float* out_f = (float*)d_out;

    const int* src_f = fei;
    const int* dst_f = fei + Ef;
    const int* src_p = pei;
    const int* dst_p = pei + Ep;

    // zero counter + deg in one fill (contiguous carves, 256-aligned)
    hipMemsetAsync(counter, 0, 256 + (size_t)n2 * 4, stream);

    int prepWork = 128 * 2048 + 2 * 256 * 128;
    prep_deg<<<(prepWork + Etot + 255) / 256, 256, 0, stream>>>(
        ip_w, gf_wsrc, gf_wdst, gp_wsrc, gp_wdst, Bt1, Bf, Bp,
        dst_f, Ef, dst_p, Ep, deg, N);

    seg_assign<<<(n2 + 255) / 256, 256, 0, stream>>>(deg, offs, cur, counter, n2);

    int gb1 = (N + 63) / 64;
    int fillb = (Etot + 255) / 256;
    gemm_fill<<<gb1 + fillb, 256, 0, stream>>>(nf, Bt1, ip_b, Bf, Bp, hshd_f, hshd_p,
                                               N, N_GENES, gb1,
                                               src_f, dst_f, few, Ef,
                                               src_p, dst_p, pew, Ep,
                                               cur, srcw, N);

    int gwaves = (n2 + 1) / 2;
    gat2<<<(gwaves + 3) / 4, 256, 0, stream>>>(offs, deg, srcw, hshd_f, hshd_p,
                                               gf_wedge, gf_attn, gf_bias,
                                               gp_wedge, gp_attn, gp_bias,
                                               h_full, out_f, N);

    final_kernel<<<(N + 3) / 4, 256, 0, stream>>>(h_full, out_f, alpha, ln_scale, ln_bias, N);
    (void)ws_size; (void)n_in; (void)out_size;
}

// Round 9
// 781.185 us; speedup vs baseline: 1.0636x; 1.0025x over previous
//
#include <hip/hip_runtime.h>
#include <hip/hip_bf16.h>

#define N_GENES 2000
#define SA 72
#define SH 136

typedef __attribute__((ext_vector_type(8))) short frag8;
typedef __attribute__((ext_vector_type(4))) float facc4;

static __device__ __forceinline__ unsigned short f2bf(float f) {
    unsigned int u = __float_as_uint(f);
    unsigned int r = (u + 0x7FFFu + ((u >> 16) & 1u)) >> 16;
    return (unsigned short)r;
}
static __device__ __forceinline__ ushort2 pk2(float a, float b) {
    __hip_bfloat162 r = __float22bfloat162_rn(float2{a, b});
    return *(ushort2*)&r;
}

// ---- weight transposes + degree histogram (deg work overlaps transpose blocks) ----
__global__ void prep_deg(const float* __restrict__ ip_w,
                         const float* __restrict__ ws_f, const float* __restrict__ wd_f,
                         const float* __restrict__ ws_p, const float* __restrict__ wd_p,
                         unsigned short* __restrict__ Bt1,
                         unsigned short* __restrict__ Bf, unsigned short* __restrict__ Bp,
                         const int* __restrict__ dst_f, int Ef,
                         const int* __restrict__ dst_p, int Ep,
                         int* __restrict__ deg, int N) {
    int idx = blockIdx.x * blockDim.x + threadIdx.x;
    if (idx < 128 * 2048) {
        int nrow = idx >> 11, k = idx & 2047;
        unsigned short v = 0;
        if (k < N_GENES) v = f2bf(ip_w[(size_t)k * 128 + nrow]);
        Bt1[idx] = v;
    } else if (idx < 128 * 2048 + 2 * 256 * 128) {
        int q = idx - 128 * 2048;
        int g = q >> 15;
        int r = (q >> 7) & 255;
        int k = q & 127;
        const float* w = (g == 0) ? (r < 128 ? ws_f : wd_f) : (r < 128 ? ws_p : wd_p);
        (g == 0 ? Bf : Bp)[(r << 7) | k] = f2bf(w[k * 128 + (r & 127)]);
    } else {
        int e = idx - (128 * 2048 + 2 * 256 * 128);
        if (e < Ef) atomicAdd(&deg[dst_f[e]], 1);
        else if (e < Ef + Ep) atomicAdd(&deg[N + dst_p[e - Ef]], 1);
    }
}

// ---- unordered segment assignment; ONE atomic per block (wave totals via LDS) ----
__global__ __launch_bounds__(256) void seg_assign(const int* __restrict__ deg,
                                                  int* __restrict__ offs,
                                                  int* __restrict__ cur,
                                                  unsigned int* __restrict__ counter, int n2) {
    __shared__ int wbase[4];
    int t = threadIdx.x;
    int i = blockIdx.x * 256 + t;
    int lane = t & 63, wv = t >> 6;
    int c = (i < n2) ? deg[i] : 0;
    int incl = c;
#pragma unroll
    for (int o = 1; o < 64; o <<= 1) {
        int y = __shfl_up(incl, o);
        if (lane >= o) incl += y;
    }
    if (lane == 63) wbase[wv] = incl;
    __syncthreads();
    if (t == 0) {
        int s0 = wbase[0], s1 = wbase[1], s2 = wbase[2], s3 = wbase[3];
        int b = (int)atomicAdd(counter, (unsigned int)(s0 + s1 + s2 + s3));
        wbase[0] = b;
        wbase[1] = b + s0;
        wbase[2] = b + s0 + s1;
        wbase[3] = b + s0 + s1 + s2;
    }
    __syncthreads();
    int start = wbase[wv] + incl - c;
    if (i < n2) { offs[i] = start; cur[i] = start; }
}

// ---- mega dispatch: blocks [0,gemmBlocks) run the fused GEMM;
//      blocks [gemmBlocks,..) run fill2 (CSR scatter, hidden under the GEMM). ----
__global__ __launch_bounds__(256) void gemm_fill(const float* __restrict__ A,
                                                 const unsigned short* __restrict__ Bt,
                                                 const float* __restrict__ bias,
                                                 const unsigned short* __restrict__ Bf,
                                                 const unsigned short* __restrict__ Bp,
                                                 unsigned short* __restrict__ Cf,
                                                 unsigned short* __restrict__ Cp,
                                                 int M, int K, int gemmBlocks,
                                                 const int* __restrict__ src_f,
                                                 const int* __restrict__ dst_f,
                                                 const float* __restrict__ ew_f, int Ef,
                                                 const int* __restrict__ src_p,
                                                 const int* __restrict__ dst_p,
                                                 const float* __restrict__ ew_p, int Ep,
                                                 int* __restrict__ cur,
                                                 int2* __restrict__ srcw, int N) {
    if (blockIdx.x >= gemmBlocks) {
        int e = (blockIdx.x - gemmBlocks) * 256 + threadIdx.x;
        if (e >= Ef + Ep) return;
        int g = (e >= Ef);
        int ee = g ? e - Ef : e;
        int d = g ? dst_p[ee] : dst_f[ee];
        int node = g ? N + d : d;
        int p = atomicAdd(&cur[node], 1);
        int s = g ? src_p[ee] : src_f[ee];
        float w = g ? ew_p[ee] : ew_f[ee];
        srcw[p] = make_int2(s, __float_as_int(w));
        return;
    }
    const int Kpad = 2048;
    __shared__ __align__(16) unsigned short lA[64 * SA];
    __shared__ __align__(16) unsigned short lH[64 * SH];
    int t = threadIdx.x, lane = t & 63, wv = t >> 6;
    int lr = lane & 15, lq = lane >> 4;
    facc4 acc[4][2];
#pragma unroll
    for (int i = 0; i < 4; i++)
#pragma unroll
        for (int j = 0; j < 2; j++) acc[i][j] = (facc4){0.f, 0.f, 0.f, 0.f};
    int row_base = blockIdx.x * 64;

    int ar_r[4], ar_c[4];
    const float* ar_p[4];
#pragma unroll
    for (int j = 0; j < 4; j++) {
        int q = j * 256 + t;
        ar_r[j] = q >> 4;
        ar_c[j] = (q & 15) * 4;
        int rg = row_base + ar_r[j];
        if (rg >= M) rg = M - 1;
        ar_p[j] = A + (size_t)rg * K + ar_c[j];
    }
    const unsigned short* bp[4];
#pragma unroll
    for (int ks = 0; ks < 2; ks++)
#pragma unroll
        for (int ni = 0; ni < 2; ni++) {
            int col = wv * 32 + ni * 16 + lr;
            bp[ks * 2 + ni] = Bt + (size_t)col * Kpad + ks * 32 + lq * 8;
        }

    float4 ar[4];
    frag8 bfr[4];
#pragma unroll
    for (int j = 0; j < 4; j++) ar[j] = *(const float4*)(ar_p[j]);
#pragma unroll
    for (int f = 0; f < 4; f++) bfr[f] = *(const frag8*)(bp[f]);

    for (int k0 = 0; k0 < Kpad; k0 += 64) {
        __syncthreads();
#pragma unroll
        for (int j = 0; j < 4; j++) {
            ushort2 u01 = pk2(ar[j].x, ar[j].y);
            ushort2 u23 = pk2(ar[j].z, ar[j].w);
            ushort4 u = {u01.x, u01.y, u23.x, u23.y};
            *(ushort4*)&lA[ar_r[j] * SA + ar_c[j]] = u;
        }
        __syncthreads();
        int kn = k0 + 64;
        frag8 bfn[4];
        if (kn < Kpad) {
#pragma unroll
            for (int j = 0; j < 4; j++) {
                int kk = kn + ar_c[j];
                float4 v = {0.f, 0.f, 0.f, 0.f};
                if (kk < K) v = *(const float4*)(ar_p[j] + kn);
                ar[j] = v;
            }
#pragma unroll
            for (int f = 0; f < 4; f++) bfn[f] = *(const frag8*)(bp[f] + kn);
        }
#pragma unroll
        for (int ks = 0; ks < 2; ks++) {
            frag8 af[4];
#pragma unroll
            for (int mi = 0; mi < 4; mi++)
                af[mi] = *(const frag8*)&lA[(mi * 16 + lr) * SA + ks * 32 + lq * 8];
#pragma unroll
            for (int mi = 0; mi < 4; mi++)
#pragma unroll
                for (int ni = 0; ni < 2; ni++)
                    acc[mi][ni] = __builtin_amdgcn_mfma_f32_16x16x32_bf16(af[mi], bfr[ks * 2 + ni], acc[mi][ni], 0, 0, 0);
        }
        if (kn < Kpad) {
#pragma unroll
            for (int f = 0; f < 4; f++) bfr[f] = bfn[f];
        }
    }
    __syncthreads();
#pragma unroll
    for (int mi = 0; mi < 4; mi++) {
#pragma unroll
        for (int r = 0; r < 4; r++) {
            int row = mi * 16 + lq * 4 + r;
#pragma unroll
            for (int ni = 0; ni < 2; ni++) {
                int col = wv * 32 + ni * 16 + lr;
                lH[row * SH + col] = f2bf(acc[mi][ni][r] + bias[col]);
            }
        }
    }
    __syncthreads();
#pragma unroll 1
    for (int g = 0; g < 2; g++) {
        const unsigned short* B2 = g ? Bp : Bf;
        unsigned short* Cb = g ? Cp : Cf;
        facc4 a2[4][4];
#pragma unroll
        for (int i = 0; i < 4; i++)
#pragma unroll
            for (int j = 0; j < 4; j++) a2[i][j] = (facc4){0.f, 0.f, 0.f, 0.f};
#pragma unroll
        for (int ks = 0; ks < 4; ks++) {
            frag8 af[4], bf[4];
#pragma unroll
            for (int mi = 0; mi < 4; mi++)
                af[mi] = *(const frag8*)&lH[(mi * 16 + lr) * SH + ks * 32 + lq * 8];
#pragma unroll
            for (int ni = 0; ni < 4; ni++)
                bf[ni] = *(const frag8*)(B2 + ((wv * 64 + ni * 16 + lr) << 7) + ks * 32 + lq * 8);
#pragma unroll
            for (int mi = 0; mi < 4; mi++)
#pragma unroll
                for (int ni = 0; ni < 4; ni++)
                    a2[mi][ni] = __builtin_amdgcn_mfma_f32_16x16x32_bf16(af[mi], bf[ni], a2[mi][ni], 0, 0, 0);
        }
#pragma unroll
        for (int mi = 0; mi < 4; mi++) {
#pragma unroll
            for (int r = 0; r < 4; r++) {
                int row = row_base + mi * 16 + lq * 4 + r;
                if (row < M) {
#pragma unroll
                    for (int ni = 0; ni < 4; ni++) {
                        int col = wv * 64 + ni * 16 + lr;
                        Cb[(size_t)row * 256 + col] = f2bf(a2[mi][ni][r]);
                    }
                }
            }
        }
    }
}

// ---- one GAT edge-stream: 2 nodes per wave (lane halves), 4 dims/lane, 8-lane heads ----
static __device__ __forceinline__ float4 gat_stream(const unsigned short* __restrict__ hshd,
                                                    const float* __restrict__ wedge,
                                                    const float* __restrict__ attn,
                                                    const float* __restrict__ bias,
                                                    const int2* __restrict__ srcw,
                                                    int s, int cnt, int onode, int d4) {
    const float LOG2E = 1.4426950408889634f;
    float4 wv4 = *(const float4*)&wedge[d4];
    float4 av4 = *(const float4*)&attn[d4];
    av4.x *= LOG2E; av4.y *= LOG2E; av4.z *= LOG2E; av4.w *= LOG2E;
    uint2 hdr = *(const uint2*)&hshd[(size_t)onode * 256 + 128 + d4];
    const float hd0 = __uint_as_float(hdr.x << 16);
    const float hd1 = __uint_as_float(hdr.x & 0xffff0000u);
    const float hd2 = __uint_as_float(hdr.y << 16);
    const float hd3 = __uint_as_float(hdr.y & 0xffff0000u);
    if (cnt <= 0) s = 0;
    int mc = max(cnt, __shfl_xor(cnt, 32));   // wave-uniform loop bound across halves
    float m = -INFINITY, l = 0.f;
    float a0 = 0.f, a1 = 0.f, a2 = 0.f, a3 = 0.f;
    if (mc > 0) {
        int last = s + (cnt > 0 ? cnt : 1) - 1;
        auto CL = [last](int j) { return j > last ? last : j; };
        int2 e0 = srcw[CL(s)], e1 = srcw[CL(s + 1)], e2 = srcw[CL(s + 2)], e3 = srcw[CL(s + 3)];
        int2 e4 = srcw[CL(s + 4)], e5 = srcw[CL(s + 5)];
        uint2 hr0 = *(const uint2*)&hshd[(size_t)e0.x * 256 + d4];
        uint2 hr1 = *(const uint2*)&hshd[(size_t)e1.x * 256 + d4];
        uint2 hr2 = *(const uint2*)&hshd[(size_t)e2.x * 256 + d4];
        uint2 hr3 = *(const uint2*)&hshd[(size_t)e3.x * 256 + d4];
        for (int i = 0; i < mc; i += 2) {
            int2 ea = srcw[CL(s + i + 6)], eb = srcw[CL(s + i + 7)];
            uint2 hr4 = *(const uint2*)&hshd[(size_t)e4.x * 256 + d4];
            uint2 hr5 = *(const uint2*)&hshd[(size_t)e5.x * 256 + d4];
            {
                float h0 = __uint_as_float(hr0.x << 16);
                float h1 = __uint_as_float(hr0.x & 0xffff0000u);
                float h2 = __uint_as_float(hr0.y << 16);
                float h3 = __uint_as_float(hr0.y & 0xffff0000u);
                float w = __int_as_float(e0.y);
                float z0 = fmaf(w, wv4.x, h0 + hd0); z0 = (z0 > 0.f) ? z0 : 0.2f * z0;
                float z1 = fmaf(w, wv4.y, h1 + hd1); z1 = (z1 > 0.f) ? z1 : 0.2f * z1;
                float z2 = fmaf(w, wv4.z, h2 + hd2); z2 = (z2 > 0.f) ? z2 : 0.2f * z2;
                float z3 = fmaf(w, wv4.w, h3 + hd3); z3 = (z3 > 0.f) ? z3 : 0.2f * z3;
                float t = fmaf(z3, av4.w, fmaf(z2, av4.z, fmaf(z1, av4.y, z0 * av4.x)));
                t += __shfl_xor(t, 1);
                t += __shfl_xor(t, 2);
                t += __shfl_xor(t, 4);
                float mn = fmaxf(m, t);
                float sc = __builtin_amdgcn_exp2f(m - mn);
                float p = __builtin_amdgcn_exp2f(t - mn);
                p = (i < cnt) ? p : 0.f;
                l = l * sc + p;
                a0 = fmaf(p, h0, a0 * sc);
                a1 = fmaf(p, h1, a1 * sc);
                a2 = fmaf(p, h2, a2 * sc);
                a3 = fmaf(p, h3, a3 * sc);
                m = mn;
            }
            {
                float h0 = __uint_as_float(hr1.x << 16);
                float h1 = __uint_as_float(hr1.x & 0xffff0000u);
                float h2 = __uint_as_float(hr1.y << 16);
                float h3 = __uint_as_float(hr1.y & 0xffff0000u);
                float w = __int_as_float(e1.y);
                float z0 = fmaf(w, wv4.x, h0 + hd0); z0 = (z0 > 0.f) ? z0 : 0.2f * z0;
                float z1 = fmaf(w, wv4.y, h1 + hd1); z1 = (z1 > 0.f) ? z1 : 0.2f * z1;
                float z2 = fmaf(w, wv4.z, h2 + hd2); z2 = (z2 > 0.f) ? z2 : 0.2f * z2;
                float z3 = fmaf(w, wv4.w, h3 + hd3); z3 = (z3 > 0.f) ? z3 : 0.2f * z3;
                float t = fmaf(z3, av4.w, fmaf(z2, av4.z, fmaf(z1, av4.y, z0 * av4.x)));
                t += __shfl_xor(t, 1);
                t += __shfl_xor(t, 2);
                t += __shfl_xor(t, 4);
                float mn = fmaxf(m, t);
                float sc = __builtin_amdgcn_exp2f(m - mn);
                float p = __builtin_amdgcn_exp2f(t - mn);
                p = (i + 1 < cnt) ? p : 0.f;
                l = l * sc + p;
                a0 = fmaf(p, h0, a0 * sc);
                a1 = fmaf(p, h1, a1 * sc);
                a2 = fmaf(p, h2, a2 * sc);
                a3 = fmaf(p, h3, a3 * sc);
                m = mn;
            }
            e0 = e2; e1 = e3; e2 = e4; e3 = e5; e4 = ea; e5 = eb;
            hr0 = hr2; hr1 = hr3; hr2 = hr4; hr3 = hr5;
        }
    }
    float inv = 1.f / (l + 1e-16f);
    const float4 bv = *(const float4*)&bias[d4];
    float4 o;
    o.x = fmaf(a0, inv, bv.x);
    o.y = fmaf(a1, inv, bv.y);
    o.z = fmaf(a2, inv, bv.z);
    o.w = fmaf(a3, inv, bv.w);
    return o;
}

// ---- fused GAT(full)+GAT(pruned)+combine+ELU+LayerNorm: node pair per wave ----
__global__ __launch_bounds__(256) void gat_final(const int* __restrict__ offs,
                                                 const int* __restrict__ deg,
                                                 const int2* __restrict__ srcw,
                                                 const unsigned short* __restrict__ hshd_f,
                                                 const unsigned short* __restrict__ hshd_p,
                                                 const float* __restrict__ wedge_f,
                                                 const float* __restrict__ attn_f,
                                                 const float* __restrict__ bias_f,
                                                 const float* __restrict__ wedge_p,
                                                 const float* __restrict__ attn_p,
                                                 const float* __restrict__ bias_p,
                                                 const float* __restrict__ alpha_p,
                                                 const float* __restrict__ scale,
                                                 const float* __restrict__ beta,
                                                 float* __restrict__ out, int N) {
    int wid = blockIdx.x * 4 + (threadIdx.x >> 6);
    if (wid * 2 >= N) return;
    int lane = threadIdx.x & 63;
    int half = lane >> 5;
    int wl = lane & 31;
    int node = wid * 2 + half;
    bool valid = node < N;
    int nc = valid ? node : N - 1;
    int d4 = wl * 4;
    int sF = offs[nc], cF = valid ? deg[nc] : 0;
    float4 f = gat_stream(hshd_f, wedge_f, attn_f, bias_f, srcw, sF, cF, nc, d4);
    int sP = offs[N + nc], cP = valid ? deg[N + nc] : 0;
    float4 p = gat_stream(hshd_p, wedge_p, attn_p, bias_p, srcw, sP, cP, nc, d4);
    float a = *alpha_p;
    float x0 = (1.f - a) * f.x + a * p.x;
    float x1 = (1.f - a) * f.y + a * p.y;
    float x2 = (1.f - a) * f.z + a * p.z;
    float x3 = (1.f - a) * f.w + a * p.w;
    x0 = (x0 > 0.f) ? x0 : expm1f(x0);
    x1 = (x1 > 0.f) ? x1 : expm1f(x1);
    x2 = (x2 > 0.f) ? x2 : expm1f(x2);
    x3 = (x3 > 0.f) ? x3 : expm1f(x3);
    float sm = x0 + x1 + x2 + x3;
#pragma unroll
    for (int o = 16; o >= 1; o >>= 1) sm += __shfl_xor(sm, o);   // within 32-lane half
    float mu = sm * (1.f / 128.f);
    float d0 = x0 - mu, d1 = x1 - mu, d2 = x2 - mu, d3 = x3 - mu;
    float v = d0 * d0 + d1 * d1 + d2 * d2 + d3 * d3;
#pragma unroll
    for (int o = 16; o >= 1; o >>= 1) v += __shfl_xor(v, o);
    float rstd = rsqrtf(v * (1.f / 128.f) + 1e-6f);
    const float4 sv = *(const float4*)&scale[d4];
    const float4 bv = *(const float4*)&beta[d4];
    if (valid) {
        float4 o4;
        o4.x = fmaf(d0 * rstd, sv.x, bv.x);
        o4.y = fmaf(d1 * rstd, sv.y, bv.y);
        o4.z = fmaf(d2 * rstd, sv.z, bv.z);
        o4.w = fmaf(d3 * rstd, sv.w, bv.w);
        *(float4*)&out[(size_t)node * 128 + d4] = o4;
    }
}

extern "C" void kernel_launch(void* const* d_in, const int* in_sizes, int n_in,
                              void* d_out, int out_size, void* d_ws, size_t ws_size,
                              hipStream_t stream) {
    const float* nf = (const float*)d_in[0];
    const int* fei = (const int*)d_in[1];
    const float* few = (const float*)d_in[2];
    const int* pei = (const int*)d_in[3];
    const float* pew = (const float*)d_in[4];
    const float* alpha = (const float*)d_in[5];
    const float* ip_w = (const float*)d_in[6];
    const float* ip_b = (const float*)d_in[7];
    const float* gf_wsrc = (const float*)d_in[8];
    const float* gf_wdst = (const float*)d_in[9];
    const float* gf_wedge = (const float*)d_in[10];
    const float* gf_attn = (const float*)d_in[11];
    const float* gf_bias = (const float*)d_in[12];
    const float* gp_wsrc = (const float*)d_in[13];
    const float* gp_wdst = (const float*)d_in[14];
    const float* gp_wedge = (const float*)d_in[15];
    const float* gp_attn = (const float*)d_in[16];
    const float* gp_bias = (const float*)d_in[17];
    const float* ln_scale = (const float*)d_in[18];
    const float* ln_bias = (const float*)d_in[19];

    const int N = in_sizes[0] / N_GENES;
    const int Ef = in_sizes[1] / 2;
    const int Ep = in_sizes[3] / 2;
    const int Etot = Ef + Ep;
    const int n2 = 2 * N;

    char* base = (char*)d_ws;
    size_t off = 0;
    auto carve = [&](size_t bytes) -> char* {
        char* p = base + off;
        off = (off + bytes + 255) & ~(size_t)255;
        return p;
    };
    unsigned short* Bt1 = (unsigned short*)carve((size_t)128 * 2048 * 2);
    unsigned short* Bf = (unsigned short*)carve(256 * 128 * 2);
    unsigned short* Bp = (unsigned short*)carve(256 * 128 * 2);
    unsigned short* hshd_f = (unsigned short*)carve((size_t)N * 256 * 2);
    unsigned short* hshd_p = (unsigned short*)carve((size_t)N * 256 * 2);
    unsigned int* counter = (unsigned int*)carve(4);      // adjacent to deg: one memset covers both
    int* deg = (int*)carve((size_t)n2 * 4);
    int* offs = (int*)carve((size_t)n2 * 4);
    int* cur = (int*)carve((size_t)n2 * 4);
    int2* srcw = (int2*)carve((size_t)Etot * 8);
    float* out_f = (float*)d_out;

    const int* src_f = fei;
    const int* dst_f = fei + Ef;
    const int* src_p = pei;
    const int* dst_p = pei + Ep;

    // zero counter + deg in one fill (contiguous carves, 256-aligned)
    hipMemsetAsync(counter, 0, 256 + (size_t)n2 * 4, stream);

    int prepWork = 128 * 2048 + 2 * 256 * 128;
    prep_deg<<<(prepWork + Etot + 255) / 256, 256, 0, stream>>>(
        ip_w, gf_wsrc, gf_wdst, gp_wsrc, gp_wdst, Bt1, Bf, Bp,
        dst_f, Ef, dst_p, Ep, deg, N);

    seg_assign<<<(n2 + 255) / 256, 256, 0, stream>>>(deg, offs, cur, counter, n2);

    int gb1 = (N + 63) / 64;
    int fillb = (Etot + 255) / 256;
    gemm_fill<<<gb1 + fillb, 256, 0, stream>>>(nf, Bt1, ip_b, Bf, Bp, hshd_f, hshd_p,
                                               N, N_GENES, gb1,
                                               src_f, dst_f, few, Ef,
                                               src_p, dst_p, pew, Ep,
                                               cur, srcw, N);

    int gwaves = (N + 1) / 2;   // one wave per node pair, both graphs + LN fused
    gat_final<<<(gwaves + 3) / 4, 256, 0, stream>>>(offs, deg, srcw, hshd_f, hshd_p,
                                                    gf_wedge, gf_attn, gf_bias,
                                                    gp_wedge, gp_attn, gp_bias,
                                                    alpha, ln_scale, ln_bias, out_f, N);
    (void)ws_size; (void)n_in; (void)out_size;
}